// Round 6
// baseline (3215.443 us; speedup 1.0000x reference)
//
#include <hip/hip_runtime.h>
#include <hip/hip_bf16.h>
#include <stdint.h>

typedef __bf16 bf16_t;
typedef __attribute__((ext_vector_type(8))) __bf16 bf16x8;
typedef __attribute__((ext_vector_type(4))) __bf16 bf16x4;
typedef __attribute__((ext_vector_type(4))) float f32x4;
typedef __attribute__((ext_vector_type(8))) unsigned short u16x8;

#define M_TOK 2304
#define DV    1024
#define DLAT  4096
#define VOCAB 32000

__device__ __forceinline__ float bf2f(unsigned short u) {
  union { unsigned int i; float f; } v; v.i = ((unsigned int)u) << 16; return v.f;
}
__device__ __forceinline__ bf16_t f2bf(float f) { return (bf16_t)f; }

constexpr int BM = 96, BN = 128, BK = 32;
constexpr int SA = 40;   // padded LDS row stride (80 B): frag reads 2-way (free)

// AMODE: 0 = A bf16 (K-contig), 1 = A f32 (K-contig, convert)
// BMODE: 0 = B f32 NT ([N][K]), 1 = B f32 NN ([K][N], transpose-stage)
// EPI:   0 = f32 store + bias, 1 = bf16 store, 2 = f32 store (split: Cp/Cp2 by s)
template<int AMODE, int BMODE, int EPI>
__global__ void __launch_bounds__(256, 4)
gemm_k(const void* __restrict__ Ap, const float* __restrict__ Bp,
       void* __restrict__ Cp, void* __restrict__ Cp2,
       const float* __restrict__ bias,
       int Ksplit, int lda, int ldb, int ldc, int Mt, int Nt)
{
  __shared__ __align__(16) bf16_t Al[2][BM * SA];  // 15360 B
  __shared__ __align__(16) bf16_t Bl[2][BN * SA];  // 20480 B

  // bijective XCD-chunked swizzle (m204)
  const int nwg = gridDim.x;
  const int orig = blockIdx.x;
  const int q = nwg >> 3, r = nwg & 7;
  const int xcd = orig & 7, idx = orig >> 3;
  const int wg = (xcd < r ? xcd * (q + 1) : r * (q + 1) + (xcd - r) * q) + idx;
  const int mt = wg % Mt;
  const int nt = (wg / Mt) % Nt;
  const int sp = wg / (Mt * Nt);          // split-K index (0 when no split)
  const int m0 = mt * BM, n0 = nt * BN;
  const int kbase = sp * Ksplit;

  const int t    = threadIdx.x;
  const int lane = t & 63, wv = t >> 6;
  const int wm = wv >> 1, wn = wv & 1;     // wave grid 2(M) x 2(N); per-wave 48x64
  const int lr = lane & 15, kc = lane >> 4;

  f32x4 acc[3][4];
#pragma unroll
  for (int i = 0; i < 3; ++i)
#pragma unroll
    for (int j = 0; j < 4; ++j)
#pragma unroll
      for (int x = 0; x < 4; ++x) acc[i][j][x] = 0.0f;

  const int ar = t >> 1, ah = t & 1;       // A staging: row, k-half
  const bool a_act = (t < 192);            // 192 threads stage 96 rows
  const int bn_r = t >> 1, bn_h = t & 1;   // B NT: n-row, k-half
  const int tv = t & 7, te = t >> 3;       // B NN: k-group(4), n-group(4 cols)

  bf16x8 a_bf0, a_bf1;            // AMODE 0
  f32x4  a_f0, a_f1, a_f2, a_f3;  // AMODE 1
  f32x4  b_f0, b_f1, b_f2, b_f3;  // B loads

  const int NT = Ksplit / BK;

  auto LOADS = [&](int kt) {
    const int k0 = kbase + kt * BK;
    if (a_act) {
      if (AMODE == 0) {
        const bf16_t* asrc = (const bf16_t*)Ap + (size_t)(m0 + ar) * lda + k0 + ah * 16;
        a_bf0 = *(const bf16x8*)(asrc);
        a_bf1 = *(const bf16x8*)(asrc + 8);
      } else {
        const float* asrc = (const float*)Ap + (size_t)(m0 + ar) * lda + k0 + ah * 16;
        a_f0 = *(const f32x4*)(asrc);     a_f1 = *(const f32x4*)(asrc + 4);
        a_f2 = *(const f32x4*)(asrc + 8); a_f3 = *(const f32x4*)(asrc + 12);
      }
    }
    if (BMODE == 0) {
      const float* bsrc = Bp + (size_t)(n0 + bn_r) * ldb + k0 + bn_h * 16;
      b_f0 = *(const f32x4*)(bsrc);     b_f1 = *(const f32x4*)(bsrc + 4);
      b_f2 = *(const f32x4*)(bsrc + 8); b_f3 = *(const f32x4*)(bsrc + 12);
    } else {
      const float* bsrc = Bp + (size_t)(k0 + tv * 4) * ldb + n0 + te * 4;
      b_f0 = *(const f32x4*)(bsrc);
      b_f1 = *(const f32x4*)(bsrc + (size_t)ldb);
      b_f2 = *(const f32x4*)(bsrc + (size_t)2 * ldb);
      b_f3 = *(const f32x4*)(bsrc + (size_t)3 * ldb);
    }
  };

  auto STORE_STAGE = [&](int nb) {
    if (a_act) {
      bf16x8 w0, w1;
      if (AMODE == 0) {
        w0 = a_bf0; w1 = a_bf1;
      } else {
#pragma unroll
        for (int c = 0; c < 4; ++c) {
          w0[c] = f2bf(a_f0[c]); w0[c + 4] = f2bf(a_f1[c]);
          w1[c] = f2bf(a_f2[c]); w1[c + 4] = f2bf(a_f3[c]);
        }
      }
      bf16_t* dst = &Al[nb][ar * SA + ah * 16];
      *(bf16x8*)(dst)     = w0;
      *(bf16x8*)(dst + 8) = w1;
    }
    if (BMODE == 0) {
      bf16x8 w0, w1;
#pragma unroll
      for (int c = 0; c < 4; ++c) {
        w0[c] = f2bf(b_f0[c]); w0[c + 4] = f2bf(b_f1[c]);
        w1[c] = f2bf(b_f2[c]); w1[c + 4] = f2bf(b_f3[c]);
      }
      bf16_t* dst = &Bl[nb][bn_r * SA + bn_h * 16];
      *(bf16x8*)(dst)     = w0;
      *(bf16x8*)(dst + 8) = w1;
    } else {
#pragma unroll
      for (int i = 0; i < 4; ++i) {
        bf16x4 w4;
        w4[0] = f2bf(b_f0[i]); w4[1] = f2bf(b_f1[i]);
        w4[2] = f2bf(b_f2[i]); w4[3] = f2bf(b_f3[i]);
        *(bf16x4*)(&Bl[nb][(te * 4 + i) * SA + tv * 4]) = w4;
      }
    }
  };

  auto COMPUTE = [&](int nb) {
    bf16x8 af[3], bfv[4];
#pragma unroll
    for (int f = 0; f < 3; ++f)
      af[f] = *(const bf16x8*)(&Al[nb][(wm * 48 + f * 16 + lr) * SA + kc * 8]);
#pragma unroll
    for (int f = 0; f < 4; ++f)
      bfv[f] = *(const bf16x8*)(&Bl[nb][(wn * 64 + f * 16 + lr) * SA + kc * 8]);
#pragma unroll
    for (int i = 0; i < 3; ++i)
#pragma unroll
      for (int j = 0; j < 4; ++j)
        acc[i][j] = __builtin_amdgcn_mfma_f32_16x16x32_bf16(af[i], bfv[j], acc[i][j], 0, 0, 0);
  };

  LOADS(0);
  STORE_STAGE(0);
  __syncthreads();
  int cur = 0;
  for (int kt = 0; kt < NT; ++kt) {
    const bool more = (kt + 1) < NT;
    if (more) LOADS(kt + 1);        // issue next-tile loads under MFMA
    COMPUTE(cur);
    if (more) STORE_STAGE(cur ^ 1);
    __syncthreads();
    cur ^= 1;
  }

  // epilogue
  float* Cout;
  if (EPI == 2) Cout = (sp == 0) ? (float*)Cp : (float*)Cp2;
  else          Cout = (float*)Cp;
#pragma unroll
  for (int j = 0; j < 4; ++j) {
    const int col = n0 + wn * 64 + j * 16 + lr;
    float bv = 0.0f;
    if (EPI == 0) bv = bias[col];
#pragma unroll
    for (int i = 0; i < 3; ++i) {
      const int row = m0 + wm * 48 + i * 16 + kc * 4;
      f32x4 a4 = acc[i][j];
      if (EPI == 0) {
#pragma unroll
        for (int x = 0; x < 4; ++x) Cout[(size_t)(row + x) * ldc + col] = a4[x] + bv;
      } else if (EPI == 1) {
        bf16_t* C = (bf16_t*)Cp;
#pragma unroll
        for (int x = 0; x < 4; ++x) C[(size_t)(row + x) * ldc + col] = f2bf(a4[x]);
      } else {
#pragma unroll
        for (int x = 0; x < 4; ++x) Cout[(size_t)(row + x) * ldc + col] = a4[x];
      }
    }
  }
}

// -------- out += partial (split-K reduction), f32 --------
__global__ void __launch_bounds__(256)
addk(float* __restrict__ out, const float* __restrict__ part, int n4)
{
  const int stride = gridDim.x * 256;
  for (int i = blockIdx.x * 256 + threadIdx.x; i < n4; i += stride) {
    f32x4 a = *(const f32x4*)(out + i * 4);
    f32x4 b = *(const f32x4*)(part + i * 4);
#pragma unroll
    for (int x = 0; x < 4; ++x) a[x] += b[x];
    *(f32x4*)(out + i * 4) = a;
  }
}

// -------- LayerNorm over last dim (4096), f32 in -> bf16 out --------
__global__ void __launch_bounds__(256)
ln_k(const float* __restrict__ x, bf16_t* __restrict__ xn)
{
  __shared__ float sm[4];
  const int row = blockIdx.x, t = threadIdx.x;
  const float* xr = x + (size_t)row * DLAT;
  f32x4 v[4];
#pragma unroll
  for (int i = 0; i < 4; ++i) v[i] = *(const f32x4*)(xr + (t + i * 256) * 4);

  float s = 0.0f;
#pragma unroll
  for (int i = 0; i < 4; ++i)
#pragma unroll
    for (int j = 0; j < 4; ++j) s += v[i][j];
#pragma unroll
  for (int o = 32; o > 0; o >>= 1) s += __shfl_xor(s, o, 64);
  if ((t & 63) == 0) sm[t >> 6] = s;
  __syncthreads();
  const float mean = (sm[0] + sm[1] + sm[2] + sm[3]) * (1.0f / DLAT);
  __syncthreads();

  float qv = 0.0f;
#pragma unroll
  for (int i = 0; i < 4; ++i)
#pragma unroll
    for (int j = 0; j < 4; ++j) { float d = v[i][j] - mean; qv += d * d; }
#pragma unroll
  for (int o = 32; o > 0; o >>= 1) qv += __shfl_xor(qv, o, 64);
  if ((t & 63) == 0) sm[t >> 6] = qv;
  __syncthreads();
  const float varr = (sm[0] + sm[1] + sm[2] + sm[3]) * (1.0f / DLAT);
  const float rs = rsqrtf(varr + 1e-5f);

  bf16_t* outr = xn + (size_t)row * DLAT;
#pragma unroll
  for (int i = 0; i < 4; ++i) {
    bf16x4 o;
#pragma unroll
    for (int j = 0; j < 4; ++j) o[j] = f2bf((v[i][j] - mean) * rs);
    *(bf16x4*)(outr + (t + i * 256) * 4) = o;
  }
}

// -------- row softmax over V=32000, bf16 in-place, row staged in LDS --------
__global__ void __launch_bounds__(256)
softmax_k(bf16_t* __restrict__ L)
{
  __shared__ __align__(16) bf16_t rs_[VOCAB];   // 64000 B
  __shared__ float sm[4];
  const int row = blockIdx.x, t = threadIdx.x;
  bf16_t* lrow = L + (size_t)row * VOCAB;
  const int NF = VOCAB / 8;   // 4000

  float m = -3.0e38f;
  for (int f = t; f < NF; f += 256) {
    u16x8 u = *(const u16x8*)(&lrow[f * 8]);
    *(u16x8*)(&rs_[f * 8]) = u;
#pragma unroll
    for (int j = 0; j < 8; ++j) m = fmaxf(m, bf2f(u[j]));
  }
#pragma unroll
  for (int o = 32; o > 0; o >>= 1) m = fmaxf(m, __shfl_xor(m, o, 64));
  if ((t & 63) == 0) sm[t >> 6] = m;
  __syncthreads();
  m = fmaxf(fmaxf(sm[0], sm[1]), fmaxf(sm[2], sm[3]));
  __syncthreads();

  float s = 0.0f;
  for (int f = t; f < NF; f += 256) {
    u16x8 u = *(const u16x8*)(&rs_[f * 8]);
#pragma unroll
    for (int j = 0; j < 8; ++j) s += __expf(bf2f(u[j]) - m);
  }
#pragma unroll
  for (int o = 32; o > 0; o >>= 1) s += __shfl_xor(s, o, 64);
  if ((t & 63) == 0) sm[t >> 6] = s;
  __syncthreads();
  const float inv = 1.0f / (sm[0] + sm[1] + sm[2] + sm[3]);

  for (int f = t; f < NF; f += 256) {
    u16x8 u = *(const u16x8*)(&rs_[f * 8]);
    bf16x8 o;
#pragma unroll
    for (int j = 0; j < 8; ++j) o[j] = f2bf(__expf(bf2f(u[j]) - m) * inv);
    *(bf16x8*)(&lrow[f * 8]) = o;
  }
}

extern "C" void kernel_launch(void* const* d_in, const int* in_sizes, int n_in,
                              void* d_out, int out_size, void* d_ws, size_t ws_size,
                              hipStream_t stream)
{
  (void)in_sizes; (void)n_in; (void)out_size; (void)ws_size;
  const float* vision = (const float*)d_in[0];   // [2304][1024]
  const float* W1w    = (const float*)d_in[1];   // [4096][1024]
  const float* W1b    = (const float*)d_in[2];   // [4096]
  const float* W2w    = (const float*)d_in[3];   // [32000][4096]
  const float* Emb    = (const float*)d_in[4];   // [32000][4096]
  float* out = (float*)d_out;                    // [2304][4096]

  char* ws = (char*)d_ws;
  bf16_t* xn     = (bf16_t*)ws;                             // 18,874,368 B
  bf16_t* logits = (bf16_t*)(ws + 18874368);                // 147,456,000 B
  float*  xbuf   = (float*)(ws + 18874368 + 147456000);     // 37,748,736 B

  const int Mt = M_TOK / BM;  // 24

  // 1) x = vision @ W1^T + b   (M=2304, N=4096, K=1024) — grid 768
  gemm_k<1, 0, 0><<<dim3(Mt * (DLAT / BN)), dim3(256), 0, stream>>>(
      vision, W1w, xbuf, nullptr, W1b, DV, DV, DV, DLAT, Mt, DLAT / BN);

  // 2) xn = LayerNorm(x) -> bf16
  ln_k<<<dim3(M_TOK), dim3(256), 0, stream>>>(xbuf, xn);

  // 3) logits = xn @ W2^T -> bf16   (M=2304, N=32000, K=4096) — grid 6000
  gemm_k<0, 0, 1><<<dim3(Mt * (VOCAB / BN)), dim3(256), 0, stream>>>(
      xn, W2w, logits, nullptr, nullptr, DLAT, DLAT, DLAT, VOCAB, Mt, VOCAB / BN);

  // 4) P = softmax(logits) in place
  softmax_k<<<dim3(M_TOK), dim3(256), 0, stream>>>(logits);

  // 5) out = P @ Emb  (M=2304, N=4096, K=32000, NN) — split-K=2, grid 1536,
  //    partials: s=0 -> out, s=1 -> xbuf (dead after LN)
  gemm_k<0, 1, 2><<<dim3(Mt * (DLAT / BN) * 2), dim3(256), 0, stream>>>(
      logits, Emb, out, xbuf, nullptr, VOCAB / 2, VOCAB, DLAT, DLAT, Mt, DLAT / BN);

  // 6) out += xbuf
  addk<<<dim3(1024), dim3(256), 0, stream>>>(out, xbuf, (M_TOK * DLAT) / 4);
}

// Round 7
// 2999.480 us; speedup vs baseline: 1.0720x; 1.0720x over previous
//
#include <hip/hip_runtime.h>
#include <hip/hip_bf16.h>
#include <stdint.h>

typedef __bf16 bf16_t;
typedef __attribute__((ext_vector_type(8))) __bf16 bf16x8;
typedef __attribute__((ext_vector_type(4))) __bf16 bf16x4;
typedef __attribute__((ext_vector_type(4))) float f32x4;
typedef __attribute__((ext_vector_type(8))) unsigned short u16x8;

#define M_TOK 2304
#define DV    1024
#define DLAT  4096
#define VOCAB 32000

__device__ __forceinline__ float bf2f(unsigned short u) {
  union { unsigned int i; float f; } v; v.i = ((unsigned int)u) << 16; return v.f;
}
__device__ __forceinline__ bf16_t f2bf(float f) { return (bf16_t)f; }

constexpr int BM = 128, BN = 128, BK = 32;
constexpr int SA = 40;   // padded LDS row stride (80 B): frag reads ~2-way (free)

// Raw barrier: ds_writes made visible via lgkmcnt(0), NO vmcnt drain --
// this is what keeps the depth-2 prefetch loads in flight (T4).
__device__ __forceinline__ void bar_lds() {
  asm volatile("s_waitcnt lgkmcnt(0)" ::: "memory");
  __builtin_amdgcn_s_barrier();
}

// AMODE: 0 = A bf16 (K-contig), 1 = A f32 (K-contig, convert)
// BMODE: 0 = B f32 NT ([N][K]), 1 = B f32 NN ([K][N], transpose-stage)
// EPI:   0 = f32 store + bias, 1 = bf16 store, 2 = f32 store
template<int AMODE, int BMODE, int EPI>
__global__ void __launch_bounds__(256, 2)
gemm_k(const void* __restrict__ Ap, const float* __restrict__ Bp,
       void* __restrict__ Cp, const float* __restrict__ bias,
       int K, int lda, int ldb, int ldc, int Mt)
{
  __shared__ __align__(16) bf16_t Al[2][BM * SA];  // 2 x 10240 B
  __shared__ __align__(16) bf16_t Bl[2][BN * SA];  // 2 x 10240 B

  // bijective XCD-chunked swizzle (m204)
  const int nwg = gridDim.x;
  const int orig = blockIdx.x;
  const int q = nwg >> 3, r = nwg & 7;
  const int xcd = orig & 7, idx = orig >> 3;
  const int wg = (xcd < r ? xcd * (q + 1) : r * (q + 1) + (xcd - r) * q) + idx;
  const int mt = wg % Mt, nt = wg / Mt;   // consecutive wg: share B panel
  const int m0 = mt * BM, n0 = nt * BN;

  const int t    = threadIdx.x;
  const int lane = t & 63, wv = t >> 6;
  const int wm = wv >> 1, wn = wv & 1;     // wave grid 2(M) x 2(N); per-wave 64x64
  const int lr = lane & 15, kc = lane >> 4;

  f32x4 acc[4][4];
#pragma unroll
  for (int i = 0; i < 4; ++i)
#pragma unroll
    for (int j = 0; j < 4; ++j)
#pragma unroll
      for (int x = 0; x < 4; ++x) acc[i][j][x] = 0.0f;

  const int sr = t >> 1, sh = t & 1;       // A / B-NT staging: row, k-half
  const int tv = t & 7, te = t >> 3;       // B NN: k-group(4), n-group(4 cols)

  // ---- two named prefetch register sets (static use only; rule #20) ----
  bf16x8 s1_ab0, s1_ab1;          bf16x8 s2_ab0, s2_ab1;           // A bf16
  f32x4  s1_af0, s1_af1, s1_af2, s1_af3;                           // A f32
  f32x4  s2_af0, s2_af1, s2_af2, s2_af3;
  f32x4  s1_b0, s1_b1, s1_b2, s1_b3;                               // B f32
  f32x4  s2_b0, s2_b1, s2_b2, s2_b3;

  const int NT = K / BK;   // 32 / 128 / 1000 -- always even

  auto LOADS1 = [&](int kt) {
    const int k0 = kt * BK;
    if (AMODE == 0) {
      const bf16_t* asrc = (const bf16_t*)Ap + (size_t)(m0 + sr) * lda + k0 + sh * 16;
      s1_ab0 = *(const bf16x8*)(asrc);
      s1_ab1 = *(const bf16x8*)(asrc + 8);
    } else {
      const float* asrc = (const float*)Ap + (size_t)(m0 + sr) * lda + k0 + sh * 16;
      s1_af0 = *(const f32x4*)(asrc);     s1_af1 = *(const f32x4*)(asrc + 4);
      s1_af2 = *(const f32x4*)(asrc + 8); s1_af3 = *(const f32x4*)(asrc + 12);
    }
    if (BMODE == 0) {
      const float* bsrc = Bp + (size_t)(n0 + sr) * ldb + k0 + sh * 16;
      s1_b0 = *(const f32x4*)(bsrc);     s1_b1 = *(const f32x4*)(bsrc + 4);
      s1_b2 = *(const f32x4*)(bsrc + 8); s1_b3 = *(const f32x4*)(bsrc + 12);
    } else {
      const float* bsrc = Bp + (size_t)(k0 + tv * 4) * ldb + n0 + te * 4;
      s1_b0 = *(const f32x4*)(bsrc);
      s1_b1 = *(const f32x4*)(bsrc + (size_t)ldb);
      s1_b2 = *(const f32x4*)(bsrc + (size_t)2 * ldb);
      s1_b3 = *(const f32x4*)(bsrc + (size_t)3 * ldb);
    }
  };
  auto LOADS2 = [&](int kt) {
    const int k0 = kt * BK;
    if (AMODE == 0) {
      const bf16_t* asrc = (const bf16_t*)Ap + (size_t)(m0 + sr) * lda + k0 + sh * 16;
      s2_ab0 = *(const bf16x8*)(asrc);
      s2_ab1 = *(const bf16x8*)(asrc + 8);
    } else {
      const float* asrc = (const float*)Ap + (size_t)(m0 + sr) * lda + k0 + sh * 16;
      s2_af0 = *(const f32x4*)(asrc);     s2_af1 = *(const f32x4*)(asrc + 4);
      s2_af2 = *(const f32x4*)(asrc + 8); s2_af3 = *(const f32x4*)(asrc + 12);
    }
    if (BMODE == 0) {
      const float* bsrc = Bp + (size_t)(n0 + sr) * ldb + k0 + sh * 16;
      s2_b0 = *(const f32x4*)(bsrc);     s2_b1 = *(const f32x4*)(bsrc + 4);
      s2_b2 = *(const f32x4*)(bsrc + 8); s2_b3 = *(const f32x4*)(bsrc + 12);
    } else {
      const float* bsrc = Bp + (size_t)(k0 + tv * 4) * ldb + n0 + te * 4;
      s2_b0 = *(const f32x4*)(bsrc);
      s2_b1 = *(const f32x4*)(bsrc + (size_t)ldb);
      s2_b2 = *(const f32x4*)(bsrc + (size_t)2 * ldb);
      s2_b3 = *(const f32x4*)(bsrc + (size_t)3 * ldb);
    }
  };

  auto STORE1 = [&](int nb) {
    {
      bf16x8 w0, w1;
      if (AMODE == 0) { w0 = s1_ab0; w1 = s1_ab1; }
      else {
#pragma unroll
        for (int c = 0; c < 4; ++c) {
          w0[c] = f2bf(s1_af0[c]); w0[c + 4] = f2bf(s1_af1[c]);
          w1[c] = f2bf(s1_af2[c]); w1[c + 4] = f2bf(s1_af3[c]);
        }
      }
      bf16_t* dst = &Al[nb][sr * SA + sh * 16];
      *(bf16x8*)(dst) = w0; *(bf16x8*)(dst + 8) = w1;
    }
    if (BMODE == 0) {
      bf16x8 w0, w1;
#pragma unroll
      for (int c = 0; c < 4; ++c) {
        w0[c] = f2bf(s1_b0[c]); w0[c + 4] = f2bf(s1_b1[c]);
        w1[c] = f2bf(s1_b2[c]); w1[c + 4] = f2bf(s1_b3[c]);
      }
      bf16_t* dst = &Bl[nb][sr * SA + sh * 16];
      *(bf16x8*)(dst) = w0; *(bf16x8*)(dst + 8) = w1;
    } else {
#pragma unroll
      for (int i = 0; i < 4; ++i) {
        bf16x4 w4;
        w4[0] = f2bf(s1_b0[i]); w4[1] = f2bf(s1_b1[i]);
        w4[2] = f2bf(s1_b2[i]); w4[3] = f2bf(s1_b3[i]);
        *(bf16x4*)(&Bl[nb][(te * 4 + i) * SA + tv * 4]) = w4;
      }
    }
  };
  auto STORE2 = [&](int nb) {
    {
      bf16x8 w0, w1;
      if (AMODE == 0) { w0 = s2_ab0; w1 = s2_ab1; }
      else {
#pragma unroll
        for (int c = 0; c < 4; ++c) {
          w0[c] = f2bf(s2_af0[c]); w0[c + 4] = f2bf(s2_af1[c]);
          w1[c] = f2bf(s2_af2[c]); w1[c + 4] = f2bf(s2_af3[c]);
        }
      }
      bf16_t* dst = &Al[nb][sr * SA + sh * 16];
      *(bf16x8*)(dst) = w0; *(bf16x8*)(dst + 8) = w1;
    }
    if (BMODE == 0) {
      bf16x8 w0, w1;
#pragma unroll
      for (int c = 0; c < 4; ++c) {
        w0[c] = f2bf(s2_b0[c]); w0[c + 4] = f2bf(s2_b1[c]);
        w1[c] = f2bf(s2_b2[c]); w1[c + 4] = f2bf(s2_b3[c]);
      }
      bf16_t* dst = &Bl[nb][sr * SA + sh * 16];
      *(bf16x8*)(dst) = w0; *(bf16x8*)(dst + 8) = w1;
    } else {
#pragma unroll
      for (int i = 0; i < 4; ++i) {
        bf16x4 w4;
        w4[0] = f2bf(s2_b0[i]); w4[1] = f2bf(s2_b1[i]);
        w4[2] = f2bf(s2_b2[i]); w4[3] = f2bf(s2_b3[i]);
        *(bf16x4*)(&Bl[nb][(te * 4 + i) * SA + tv * 4]) = w4;
      }
    }
  };

  auto COMPUTE = [&](int nb) {
    bf16x8 af[4], bfv[4];
#pragma unroll
    for (int f = 0; f < 4; ++f)
      af[f] = *(const bf16x8*)(&Al[nb][(wm * 64 + f * 16 + lr) * SA + kc * 8]);
#pragma unroll
    for (int f = 0; f < 4; ++f)
      bfv[f] = *(const bf16x8*)(&Bl[nb][(wn * 64 + f * 16 + lr) * SA + kc * 8]);
    __builtin_amdgcn_s_setprio(1);
#pragma unroll
    for (int i = 0; i < 4; ++i)
#pragma unroll
      for (int j = 0; j < 4; ++j)
        acc[i][j] = __builtin_amdgcn_mfma_f32_16x16x32_bf16(af[i], bfv[j], acc[i][j], 0, 0, 0);
    __builtin_amdgcn_s_setprio(0);
  };

  // ---- depth-2 pipeline with raw barriers (counted vmcnt survives) ----
  LOADS1(0);
  LOADS2(1);        // 12 loads in flight
  STORE1(0);        // compiler waits vmcnt(6): only set1 must land
  bar_lds();

  const int NIT = NT / 2 - 1;
  for (int it = 0; it < NIT; ++it) {
    LOADS1(2 * it + 2);   // issue t+2 loads; stay in flight across 2 barriers
    COMPUTE(0);           // tile 2it from LDS buf 0
    STORE2(1);            // vmcnt(6): set2 (tile 2it+1) landed; set1 outstanding
    bar_lds();
    LOADS2(2 * it + 3);
    COMPUTE(1);
    STORE1(0);            // vmcnt(6): set1 (tile 2it+2) landed
    bar_lds();
  }
  // tail: buf0 = tile NT-2 (staged), set2 = tile NT-1 (in flight)
  COMPUTE(0);
  STORE2(1);
  bar_lds();
  COMPUTE(1);

  // epilogue
#pragma unroll
  for (int j = 0; j < 4; ++j) {
    const int col = n0 + wn * 64 + j * 16 + lr;
    float bv = 0.0f;
    if (EPI == 0) bv = bias[col];
#pragma unroll
    for (int i = 0; i < 4; ++i) {
      const int row = m0 + wm * 64 + i * 16 + kc * 4;
      f32x4 a4 = acc[i][j];
      if (EPI == 0) {
        float* C = (float*)Cp;
#pragma unroll
        for (int x = 0; x < 4; ++x) C[(size_t)(row + x) * ldc + col] = a4[x] + bv;
      } else if (EPI == 1) {
        bf16_t* C = (bf16_t*)Cp;
#pragma unroll
        for (int x = 0; x < 4; ++x) C[(size_t)(row + x) * ldc + col] = f2bf(a4[x]);
      } else {
        float* C = (float*)Cp;
#pragma unroll
        for (int x = 0; x < 4; ++x) C[(size_t)(row + x) * ldc + col] = a4[x];
      }
    }
  }
}

// -------- LayerNorm over last dim (4096), f32 in -> bf16 out --------
__global__ void __launch_bounds__(256)
ln_k(const float* __restrict__ x, bf16_t* __restrict__ xn)
{
  __shared__ float sm[4];
  const int row = blockIdx.x, t = threadIdx.x;
  const float* xr = x + (size_t)row * DLAT;
  f32x4 v[4];
#pragma unroll
  for (int i = 0; i < 4; ++i) v[i] = *(const f32x4*)(xr + (t + i * 256) * 4);

  float s = 0.0f;
#pragma unroll
  for (int i = 0; i < 4; ++i)
#pragma unroll
    for (int j = 0; j < 4; ++j) s += v[i][j];
#pragma unroll
  for (int o = 32; o > 0; o >>= 1) s += __shfl_xor(s, o, 64);
  if ((t & 63) == 0) sm[t >> 6] = s;
  __syncthreads();
  const float mean = (sm[0] + sm[1] + sm[2] + sm[3]) * (1.0f / DLAT);
  __syncthreads();

  float qv = 0.0f;
#pragma unroll
  for (int i = 0; i < 4; ++i)
#pragma unroll
    for (int j = 0; j < 4; ++j) { float d = v[i][j] - mean; qv += d * d; }
#pragma unroll
  for (int o = 32; o > 0; o >>= 1) qv += __shfl_xor(qv, o, 64);
  if ((t & 63) == 0) sm[t >> 6] = qv;
  __syncthreads();
  const float varr = (sm[0] + sm[1] + sm[2] + sm[3]) * (1.0f / DLAT);
  const float rs = rsqrtf(varr + 1e-5f);

  bf16_t* outr = xn + (size_t)row * DLAT;
#pragma unroll
  for (int i = 0; i < 4; ++i) {
    bf16x4 o;
#pragma unroll
    for (int j = 0; j < 4; ++j) o[j] = f2bf((v[i][j] - mean) * rs);
    *(bf16x4*)(outr + (t + i * 256) * 4) = o;
  }
}

// -------- row softmax over V=32000, bf16 in-place, row staged in LDS --------
__global__ void __launch_bounds__(256)
softmax_k(bf16_t* __restrict__ L)
{
  __shared__ __align__(16) bf16_t rs_[VOCAB];   // 64000 B
  __shared__ float sm[4];
  const int row = blockIdx.x, t = threadIdx.x;
  bf16_t* lrow = L + (size_t)row * VOCAB;
  const int NF = VOCAB / 8;   // 4000

  float m = -3.0e38f;
  for (int f = t; f < NF; f += 256) {
    u16x8 u = *(const u16x8*)(&lrow[f * 8]);
    *(u16x8*)(&rs_[f * 8]) = u;
#pragma unroll
    for (int j = 0; j < 8; ++j) m = fmaxf(m, bf2f(u[j]));
  }
#pragma unroll
  for (int o = 32; o > 0; o >>= 1) m = fmaxf(m, __shfl_xor(m, o, 64));
  if ((t & 63) == 0) sm[t >> 6] = m;
  __syncthreads();
  m = fmaxf(fmaxf(sm[0], sm[1]), fmaxf(sm[2], sm[3]));
  __syncthreads();

  float s = 0.0f;
  for (int f = t; f < NF; f += 256) {
    u16x8 u = *(const u16x8*)(&rs_[f * 8]);
#pragma unroll
    for (int j = 0; j < 8; ++j) s += __expf(bf2f(u[j]) - m);
  }
#pragma unroll
  for (int o = 32; o > 0; o >>= 1) s += __shfl_xor(s, o, 64);
  if ((t & 63) == 0) sm[t >> 6] = s;
  __syncthreads();
  const float inv = 1.0f / (sm[0] + sm[1] + sm[2] + sm[3]);

  for (int f = t; f < NF; f += 256) {
    u16x8 u = *(const u16x8*)(&rs_[f * 8]);
    bf16x8 o;
#pragma unroll
    for (int j = 0; j < 8; ++j) o[j] = f2bf(__expf(bf2f(u[j]) - m) * inv);
    *(bf16x8*)(&lrow[f * 8]) = o;
  }
}

extern "C" void kernel_launch(void* const* d_in, const int* in_sizes, int n_in,
                              void* d_out, int out_size, void* d_ws, size_t ws_size,
                              hipStream_t stream)
{
  (void)in_sizes; (void)n_in; (void)out_size; (void)ws_size;
  const float* vision = (const float*)d_in[0];   // [2304][1024]
  const float* W1w    = (const float*)d_in[1];   // [4096][1024]
  const float* W1b    = (const float*)d_in[2];   // [4096]
  const float* W2w    = (const float*)d_in[3];   // [32000][4096]
  const float* Emb    = (const float*)d_in[4];   // [32000][4096]
  float* out = (float*)d_out;                    // [2304][4096]

  char* ws = (char*)d_ws;
  bf16_t* xn     = (bf16_t*)ws;                             // 18,874,368 B
  bf16_t* logits = (bf16_t*)(ws + 18874368);                // 147,456,000 B
  float*  xbuf   = (float*)(ws + 18874368 + 147456000);     // 37,748,736 B

  const int Mt = M_TOK / BM;  // 18

  // 1) x = vision @ W1^T + b   (M=2304, N=4096, K=1024) — grid 576
  gemm_k<1, 0, 0><<<dim3(Mt * (DLAT / BN)), dim3(256), 0, stream>>>(
      vision, W1w, xbuf, W1b, DV, DV, DV, DLAT, Mt);

  // 2) xn = LayerNorm(x) -> bf16
  ln_k<<<dim3(M_TOK), dim3(256), 0, stream>>>(xbuf, xn);

  // 3) logits = xn @ W2^T -> bf16   (M=2304, N=32000, K=4096) — grid 4500
  gemm_k<0, 0, 1><<<dim3(Mt * (VOCAB / BN)), dim3(256), 0, stream>>>(
      xn, W2w, logits, nullptr, DLAT, DLAT, DLAT, VOCAB, Mt);

  // 4) P = softmax(logits) in place
  softmax_k<<<dim3(M_TOK), dim3(256), 0, stream>>>(logits);

  // 5) out = P @ Emb   (M=2304, N=4096, K=32000, NN) — grid 576
  gemm_k<0, 1, 2><<<dim3(Mt * (DLAT / BN)), dim3(256), 0, stream>>>(
      logits, Emb, out, nullptr, VOCAB, VOCAB, DLAT, DLAT, Mt);
}

// Round 8
// 2134.984 us; speedup vs baseline: 1.5061x; 1.4049x over previous
//
#include <hip/hip_runtime.h>
#include <hip/hip_bf16.h>
#include <stdint.h>

typedef __bf16 bf16_t;
typedef __attribute__((ext_vector_type(8))) __bf16 bf16x8;
typedef __attribute__((ext_vector_type(4))) __bf16 bf16x4;
typedef __attribute__((ext_vector_type(4))) float f32x4;
typedef __attribute__((ext_vector_type(8))) unsigned short u16x8;

#define M_TOK 2304
#define DV    1024
#define DLAT  4096
#define VOCAB 32000

__device__ __forceinline__ float bf2f(unsigned short u) {
  union { unsigned int i; float f; } v; v.i = ((unsigned int)u) << 16; return v.f;
}
__device__ __forceinline__ bf16_t f2bf(float f) { return (bf16_t)f; }

// async global->LDS, 16B per lane; LDS dest = wave-uniform base + lane*16
#define GLOAD16(gp, lp) \
  __builtin_amdgcn_global_load_lds( \
      (const __attribute__((address_space(1))) unsigned int*)(const void*)(gp), \
      (__attribute__((address_space(3))) unsigned int*)(void*)(lp), 16, 0, 0)

// ======================= bf16 x bf16 NT GEMM (m97 structure) ================
// A [M][K] bf16 row-major, B [N][K] bf16 row-major, K == lda == ldb.
// BM=96, BN=128, BK=32. global_load_lds staging, linear LDS, 1 barrier/tile.
// EPI: 1 = bf16 store, 2 = f32 store.
constexpr int GBM = 96, GBN = 128, GBK = 32;

template<int EPI>
__global__ void __launch_bounds__(256, 4)
gemm_bb(const bf16_t* __restrict__ Ap, const bf16_t* __restrict__ Bp,
        void* __restrict__ Cp, int K, int ldc, int Mt)
{
  __shared__ __align__(16) bf16_t Al[2][GBM * GBK];  // 2 x 6144 B
  __shared__ __align__(16) bf16_t Bl[2][GBN * GBK];  // 2 x 8192 B

  // bijective XCD-chunked swizzle (m204)
  const int nwg = gridDim.x;
  const int orig = blockIdx.x;
  const int q = nwg >> 3, r = nwg & 7;
  const int xcd = orig & 7, idx = orig >> 3;
  const int wg = (xcd < r ? xcd * (q + 1) : r * (q + 1) + (xcd - r) * q) + idx;
  const int mt = wg % Mt, nt = wg / Mt;   // mt fastest: consecutive wg share B panel
  const int m0 = mt * GBM, n0 = nt * GBN;

  const int t    = threadIdx.x;
  const int lane = t & 63, wv = t >> 6;
  const int wm = wv >> 1, wn = wv & 1;     // wave grid 2(M) x 2(N): per-wave 48x64
  const int lr = lane & 15, kc = lane >> 4;

  f32x4 acc[3][4];
#pragma unroll
  for (int i = 0; i < 3; ++i)
#pragma unroll
    for (int j = 0; j < 4; ++j)
#pragma unroll
      for (int x = 0; x < 4; ++x) acc[i][j][x] = 0.0f;

  // staging geometry: 16 B per lane; 4-lane groups cover one 64 B row-chunk.
  const int rql = lane >> 2;          // row within 32-row group
  const int cb  = (lane & 3) * 16;    // byte offset within the 64 B row chunk
  const size_t rstride = (size_t)K * 2;   // row byte stride (lda == ldb == K)

  const int NT = K / GBK;

  auto STAGE = [&](int kt, int nb) {
    const size_t kb = (size_t)kt * GBK * 2;   // k byte offset
    if (wv < 3) {   // A: 3 waves x 32 rows = 96
      const char* g1 = (const char*)Ap + (size_t)(m0 + wv * 32 + rql) * rstride + kb + cb;
      char* l1 = (char*)&Al[nb][0] + wv * 2048;
      GLOAD16(g1, l1);
      GLOAD16(g1 + 16 * rstride, l1 + 1024);
    }
    {               // B: 4 waves x 32 rows = 128
      const char* g1 = (const char*)Bp + (size_t)(n0 + wv * 32 + rql) * rstride + kb + cb;
      char* l1 = (char*)&Bl[nb][0] + wv * 2048;
      GLOAD16(g1, l1);
      GLOAD16(g1 + 16 * rstride, l1 + 1024);
    }
  };

  auto COMPUTE = [&](int nb) {
    bf16x8 af[3], bfv[4];
#pragma unroll
    for (int f = 0; f < 3; ++f)
      af[f] = *(const bf16x8*)(&Al[nb][(wm * 48 + f * 16 + lr) * GBK + kc * 8]);
#pragma unroll
    for (int f = 0; f < 4; ++f)
      bfv[f] = *(const bf16x8*)(&Bl[nb][(wn * 64 + f * 16 + lr) * GBK + kc * 8]);
    __builtin_amdgcn_s_setprio(1);
#pragma unroll
    for (int i = 0; i < 3; ++i)
#pragma unroll
      for (int j = 0; j < 4; ++j)
        acc[i][j] = __builtin_amdgcn_mfma_f32_16x16x32_bf16(af[i], bfv[j], acc[i][j], 0, 0, 0);
    __builtin_amdgcn_s_setprio(0);
  };

  STAGE(0, 0);
  __syncthreads();                 // drains vmcnt: buf0 ready
  int cur = 0;
  for (int kt = 0; kt < NT; ++kt) {
    const bool more = (kt + 1) < NT;
    if (more) STAGE(kt + 1, cur ^ 1);  // async loads fly under COMPUTE
    COMPUTE(cur);
    __syncthreads();               // vmcnt(0)+lgkmcnt(0)+barrier: next buf ready
    cur ^= 1;
  }

  // epilogue
#pragma unroll
  for (int j = 0; j < 4; ++j) {
    const int col = n0 + wn * 64 + j * 16 + lr;
#pragma unroll
    for (int i = 0; i < 3; ++i) {
      const int row = m0 + wm * 48 + i * 16 + kc * 4;
      f32x4 a4 = acc[i][j];
      if (EPI == 1) {
        bf16_t* C = (bf16_t*)Cp;
#pragma unroll
        for (int x = 0; x < 4; ++x) C[(size_t)(row + x) * ldc + col] = f2bf(a4[x]);
      } else {
        float* C = (float*)Cp;
#pragma unroll
        for (int x = 0; x < 4; ++x) C[(size_t)(row + x) * ldc + col] = a4[x];
      }
    }
  }
}

// ================== generic f32-input GEMM (R6 version; GEMM1 + fallback) ==
constexpr int BM = 128, BN = 128, BK = 32;
constexpr int SA = 40;

__device__ __forceinline__ void bar_lds() {
  asm volatile("s_waitcnt lgkmcnt(0)" ::: "memory");
  __builtin_amdgcn_s_barrier();
}

template<int AMODE, int BMODE, int EPI>
__global__ void __launch_bounds__(256, 2)
gemm_k(const void* __restrict__ Ap, const float* __restrict__ Bp,
       void* __restrict__ Cp, const float* __restrict__ bias,
       int K, int lda, int ldb, int ldc, int Mt)
{
  __shared__ __align__(16) bf16_t Al[2][BM * SA];
  __shared__ __align__(16) bf16_t Bl[2][BN * SA];

  const int nwg = gridDim.x;
  const int orig = blockIdx.x;
  const int q = nwg >> 3, r = nwg & 7;
  const int xcd = orig & 7, idx = orig >> 3;
  const int wg = (xcd < r ? xcd * (q + 1) : r * (q + 1) + (xcd - r) * q) + idx;
  const int mt = wg % Mt, nt = wg / Mt;
  const int m0 = mt * BM, n0 = nt * BN;

  const int t    = threadIdx.x;
  const int lane = t & 63, wv = t >> 6;
  const int wm = wv >> 1, wn = wv & 1;
  const int lr = lane & 15, kc = lane >> 4;

  f32x4 acc[4][4];
#pragma unroll
  for (int i = 0; i < 4; ++i)
#pragma unroll
    for (int j = 0; j < 4; ++j)
#pragma unroll
      for (int x = 0; x < 4; ++x) acc[i][j][x] = 0.0f;

  const int sr = t >> 1, sh = t & 1;
  const int tv = t & 7, te = t >> 3;

  bf16x8 s1_ab0, s1_ab1;          bf16x8 s2_ab0, s2_ab1;
  f32x4  s1_af0, s1_af1, s1_af2, s1_af3;
  f32x4  s2_af0, s2_af1, s2_af2, s2_af3;
  f32x4  s1_b0, s1_b1, s1_b2, s1_b3;
  f32x4  s2_b0, s2_b1, s2_b2, s2_b3;

  const int NT = K / BK;

  auto LOADS1 = [&](int kt) {
    const int k0 = kt * BK;
    if (AMODE == 0) {
      const bf16_t* asrc = (const bf16_t*)Ap + (size_t)(m0 + sr) * lda + k0 + sh * 16;
      s1_ab0 = *(const bf16x8*)(asrc);
      s1_ab1 = *(const bf16x8*)(asrc + 8);
    } else {
      const float* asrc = (const float*)Ap + (size_t)(m0 + sr) * lda + k0 + sh * 16;
      s1_af0 = *(const f32x4*)(asrc);     s1_af1 = *(const f32x4*)(asrc + 4);
      s1_af2 = *(const f32x4*)(asrc + 8); s1_af3 = *(const f32x4*)(asrc + 12);
    }
    if (BMODE == 0) {
      const float* bsrc = Bp + (size_t)(n0 + sr) * ldb + k0 + sh * 16;
      s1_b0 = *(const f32x4*)(bsrc);     s1_b1 = *(const f32x4*)(bsrc + 4);
      s1_b2 = *(const f32x4*)(bsrc + 8); s1_b3 = *(const f32x4*)(bsrc + 12);
    } else {
      const float* bsrc = Bp + (size_t)(k0 + tv * 4) * ldb + n0 + te * 4;
      s1_b0 = *(const f32x4*)(bsrc);
      s1_b1 = *(const f32x4*)(bsrc + (size_t)ldb);
      s1_b2 = *(const f32x4*)(bsrc + (size_t)2 * ldb);
      s1_b3 = *(const f32x4*)(bsrc + (size_t)3 * ldb);
    }
  };
  auto LOADS2 = [&](int kt) {
    const int k0 = kt * BK;
    if (AMODE == 0) {
      const bf16_t* asrc = (const bf16_t*)Ap + (size_t)(m0 + sr) * lda + k0 + sh * 16;
      s2_ab0 = *(const bf16x8*)(asrc);
      s2_ab1 = *(const bf16x8*)(asrc + 8);
    } else {
      const float* asrc = (const float*)Ap + (size_t)(m0 + sr) * lda + k0 + sh * 16;
      s2_af0 = *(const f32x4*)(asrc);     s2_af1 = *(const f32x4*)(asrc + 4);
      s2_af2 = *(const f32x4*)(asrc + 8); s2_af3 = *(const f32x4*)(asrc + 12);
    }
    if (BMODE == 0) {
      const float* bsrc = Bp + (size_t)(n0 + sr) * ldb + k0 + sh * 16;
      s2_b0 = *(const f32x4*)(bsrc);     s2_b1 = *(const f32x4*)(bsrc + 4);
      s2_b2 = *(const f32x4*)(bsrc + 8); s2_b3 = *(const f32x4*)(bsrc + 12);
    } else {
      const float* bsrc = Bp + (size_t)(k0 + tv * 4) * ldb + n0 + te * 4;
      s2_b0 = *(const f32x4*)(bsrc);
      s2_b1 = *(const f32x4*)(bsrc + (size_t)ldb);
      s2_b2 = *(const f32x4*)(bsrc + (size_t)2 * ldb);
      s2_b3 = *(const f32x4*)(bsrc + (size_t)3 * ldb);
    }
  };

  auto STORE1 = [&](int nb) {
    {
      bf16x8 w0, w1;
      if (AMODE == 0) { w0 = s1_ab0; w1 = s1_ab1; }
      else {
#pragma unroll
        for (int c = 0; c < 4; ++c) {
          w0[c] = f2bf(s1_af0[c]); w0[c + 4] = f2bf(s1_af1[c]);
          w1[c] = f2bf(s1_af2[c]); w1[c + 4] = f2bf(s1_af3[c]);
        }
      }
      bf16_t* dst = &Al[nb][sr * SA + sh * 16];
      *(bf16x8*)(dst) = w0; *(bf16x8*)(dst + 8) = w1;
    }
    if (BMODE == 0) {
      bf16x8 w0, w1;
#pragma unroll
      for (int c = 0; c < 4; ++c) {
        w0[c] = f2bf(s1_b0[c]); w0[c + 4] = f2bf(s1_b1[c]);
        w1[c] = f2bf(s1_b2[c]); w1[c + 4] = f2bf(s1_b3[c]);
      }
      bf16_t* dst = &Bl[nb][sr * SA + sh * 16];
      *(bf16x8*)(dst) = w0; *(bf16x8*)(dst + 8) = w1;
    } else {
#pragma unroll
      for (int i = 0; i < 4; ++i) {
        bf16x4 w4;
        w4[0] = f2bf(s1_b0[i]); w4[1] = f2bf(s1_b1[i]);
        w4[2] = f2bf(s1_b2[i]); w4[3] = f2bf(s1_b3[i]);
        *(bf16x4*)(&Bl[nb][(te * 4 + i) * SA + tv * 4]) = w4;
      }
    }
  };
  auto STORE2 = [&](int nb) {
    {
      bf16x8 w0, w1;
      if (AMODE == 0) { w0 = s2_ab0; w1 = s2_ab1; }
      else {
#pragma unroll
        for (int c = 0; c < 4; ++c) {
          w0[c] = f2bf(s2_af0[c]); w0[c + 4] = f2bf(s2_af1[c]);
          w1[c] = f2bf(s2_af2[c]); w1[c + 4] = f2bf(s2_af3[c]);
        }
      }
      bf16_t* dst = &Al[nb][sr * SA + sh * 16];
      *(bf16x8*)(dst) = w0; *(bf16x8*)(dst + 8) = w1;
    }
    if (BMODE == 0) {
      bf16x8 w0, w1;
#pragma unroll
      for (int c = 0; c < 4; ++c) {
        w0[c] = f2bf(s2_b0[c]); w0[c + 4] = f2bf(s2_b1[c]);
        w1[c] = f2bf(s2_b2[c]); w1[c + 4] = f2bf(s2_b3[c]);
      }
      bf16_t* dst = &Bl[nb][sr * SA + sh * 16];
      *(bf16x8*)(dst) = w0; *(bf16x8*)(dst + 8) = w1;
    } else {
#pragma unroll
      for (int i = 0; i < 4; ++i) {
        bf16x4 w4;
        w4[0] = f2bf(s2_b0[i]); w4[1] = f2bf(s2_b1[i]);
        w4[2] = f2bf(s2_b2[i]); w4[3] = f2bf(s2_b3[i]);
        *(bf16x4*)(&Bl[nb][(te * 4 + i) * SA + tv * 4]) = w4;
      }
    }
  };

  auto COMPUTE = [&](int nb) {
    bf16x8 af[4], bfv[4];
#pragma unroll
    for (int f = 0; f < 4; ++f)
      af[f] = *(const bf16x8*)(&Al[nb][(wm * 64 + f * 16 + lr) * SA + kc * 8]);
#pragma unroll
    for (int f = 0; f < 4; ++f)
      bfv[f] = *(const bf16x8*)(&Bl[nb][(wn * 64 + f * 16 + lr) * SA + kc * 8]);
    __builtin_amdgcn_s_setprio(1);
#pragma unroll
    for (int i = 0; i < 4; ++i)
#pragma unroll
      for (int j = 0; j < 4; ++j)
        acc[i][j] = __builtin_amdgcn_mfma_f32_16x16x32_bf16(af[i], bfv[j], acc[i][j], 0, 0, 0);
    __builtin_amdgcn_s_setprio(0);
  };

  LOADS1(0);
  LOADS2(1);
  STORE1(0);
  bar_lds();

  const int NIT = NT / 2 - 1;
  for (int it = 0; it < NIT; ++it) {
    LOADS1(2 * it + 2);
    COMPUTE(0);
    STORE2(1);
    bar_lds();
    LOADS2(2 * it + 3);
    COMPUTE(1);
    STORE1(0);
    bar_lds();
  }
  COMPUTE(0);
  STORE2(1);
  bar_lds();
  COMPUTE(1);

#pragma unroll
  for (int j = 0; j < 4; ++j) {
    const int col = n0 + wn * 64 + j * 16 + lr;
    float bv = 0.0f;
    if (EPI == 0) bv = bias[col];
#pragma unroll
    for (int i = 0; i < 4; ++i) {
      const int row = m0 + wm * 64 + i * 16 + kc * 4;
      f32x4 a4 = acc[i][j];
      if (EPI == 0) {
        float* C = (float*)Cp;
#pragma unroll
        for (int x = 0; x < 4; ++x) C[(size_t)(row + x) * ldc + col] = a4[x] + bv;
      } else if (EPI == 1) {
        bf16_t* C = (bf16_t*)Cp;
#pragma unroll
        for (int x = 0; x < 4; ++x) C[(size_t)(row + x) * ldc + col] = f2bf(a4[x]);
      } else {
        float* C = (float*)Cp;
#pragma unroll
        for (int x = 0; x < 4; ++x) C[(size_t)(row + x) * ldc + col] = a4[x];
      }
    }
  }
}

// -------- stream convert f32 -> bf16 (same layout) --------
__global__ void __launch_bounds__(256)
cvt_bf16_k(const float* __restrict__ in, bf16_t* __restrict__ out, long n8)
{
  const long stride = (long)gridDim.x * 256;
  for (long i = (long)blockIdx.x * 256 + threadIdx.x; i < n8; i += stride) {
    f32x4 a = *(const f32x4*)(in + i * 8);
    f32x4 b = *(const f32x4*)(in + i * 8 + 4);
    bf16x8 o;
#pragma unroll
    for (int j = 0; j < 4; ++j) { o[j] = f2bf(a[j]); o[j + 4] = f2bf(b[j]); }
    *(bf16x8*)(out + i * 8) = o;
  }
}

// -------- Emb [32000][4096] f32  ->  EmbT [4096][32000] bf16 (LDS-tiled) ----
__global__ void __launch_bounds__(256)
embT_k(const float* __restrict__ E, bf16_t* __restrict__ ET)
{
  __shared__ bf16_t tl[64][72];   // [e_local][v_local], 144 B stride (16-aligned)
  const int vb = blockIdx.x % (VOCAB / 64);
  const int eb = blockIdx.x / (VOCAB / 64);
  const int v0 = vb * 64, e0 = eb * 64;
  const int t = threadIdx.x;

  const int rr = t >> 4, c4 = (t & 15) * 4;
#pragma unroll
  for (int p = 0; p < 4; ++p) {
    const float* src = E + (size_t)(v0 + rr + p * 16) * DLAT + e0 + c4;
    f32x4 a = *(const f32x4*)src;
#pragma unroll
    for (int j = 0; j < 4; ++j) tl[c4 + j][rr + p * 16] = f2bf(a[j]);
  }
  __syncthreads();

  const int el = t >> 3, v8 = (t & 7) * 8;
#pragma unroll
  for (int p = 0; p < 2; ++p) {
    bf16x8 o = *(const bf16x8*)(&tl[el + p * 32][v8]);
    *(bf16x8*)(ET + (size_t)(e0 + el + p * 32) * VOCAB + v0 + v8) = o;
  }
}

// -------- LayerNorm over last dim (4096), f32 in -> bf16 out --------
__global__ void __launch_bounds__(256)
ln_k(const float* __restrict__ x, bf16_t* __restrict__ xn)
{
  __shared__ float sm[4];
  const int row = blockIdx.x, t = threadIdx.x;
  const float* xr = x + (size_t)row * DLAT;
  f32x4 v[4];
#pragma unroll
  for (int i = 0; i < 4; ++i) v[i] = *(const f32x4*)(xr + (t + i * 256) * 4);

  float s = 0.0f;
#pragma unroll
  for (int i = 0; i < 4; ++i)
#pragma unroll
    for (int j = 0; j < 4; ++j) s += v[i][j];
#pragma unroll
  for (int o = 32; o > 0; o >>= 1) s += __shfl_xor(s, o, 64);
  if ((t & 63) == 0) sm[t >> 6] = s;
  __syncthreads();
  const float mean = (sm[0] + sm[1] + sm[2] + sm[3]) * (1.0f / DLAT);
  __syncthreads();

  float qv = 0.0f;
#pragma unroll
  for (int i = 0; i < 4; ++i)
#pragma unroll
    for (int j = 0; j < 4; ++j) { float d = v[i][j] - mean; qv += d * d; }
#pragma unroll
  for (int o = 32; o > 0; o >>= 1) qv += __shfl_xor(qv, o, 64);
  if ((t & 63) == 0) sm[t >> 6] = qv;
  __syncthreads();
  const float varr = (sm[0] + sm[1] + sm[2] + sm[3]) * (1.0f / DLAT);
  const float rs = rsqrtf(varr + 1e-5f);

  bf16_t* outr = xn + (size_t)row * DLAT;
#pragma unroll
  for (int i = 0; i < 4; ++i) {
    bf16x4 o;
#pragma unroll
    for (int j = 0; j < 4; ++j) o[j] = f2bf((v[i][j] - mean) * rs);
    *(bf16x4*)(outr + (t + i * 256) * 4) = o;
  }
}

// -------- row softmax over V=32000, bf16 in-place, row staged in LDS --------
__global__ void __launch_bounds__(256)
softmax_k(bf16_t* __restrict__ L)
{
  __shared__ __align__(16) bf16_t rs_[VOCAB];
  __shared__ float sm[4];
  const int row = blockIdx.x, t = threadIdx.x;
  bf16_t* lrow = L + (size_t)row * VOCAB;
  const int NF = VOCAB / 8;

  float m = -3.0e38f;
  for (int f = t; f < NF; f += 256) {
    u16x8 u = *(const u16x8*)(&lrow[f * 8]);
    *(u16x8*)(&rs_[f * 8]) = u;
#pragma unroll
    for (int j = 0; j < 8; ++j) m = fmaxf(m, bf2f(u[j]));
  }
#pragma unroll
  for (int o = 32; o > 0; o >>= 1) m = fmaxf(m, __shfl_xor(m, o, 64));
  if ((t & 63) == 0) sm[t >> 6] = m;
  __syncthreads();
  m = fmaxf(fmaxf(sm[0], sm[1]), fmaxf(sm[2], sm[3]));
  __syncthreads();

  float s = 0.0f;
  for (int f = t; f < NF; f += 256) {
    u16x8 u = *(const u16x8*)(&rs_[f * 8]);
#pragma unroll
    for (int j = 0; j < 8; ++j) s += __expf(bf2f(u[j]) - m);
  }
#pragma unroll
  for (int o = 32; o > 0; o >>= 1) s += __shfl_xor(s, o, 64);
  if ((t & 63) == 0) sm[t >> 6] = s;
  __syncthreads();
  const float inv = 1.0f / (sm[0] + sm[1] + sm[2] + sm[3]);

  for (int f = t; f < NF; f += 256) {
    u16x8 u = *(const u16x8*)(&rs_[f * 8]);
    bf16x8 o;
#pragma unroll
    for (int j = 0; j < 8; ++j) o[j] = f2bf(__expf(bf2f(u[j]) - m) * inv);
    *(bf16x8*)(&lrow[f * 8]) = o;
  }
}

extern "C" void kernel_launch(void* const* d_in, const int* in_sizes, int n_in,
                              void* d_out, int out_size, void* d_ws, size_t ws_size,
                              hipStream_t stream)
{
  (void)in_sizes; (void)n_in; (void)out_size;
  const float* vision = (const float*)d_in[0];   // [2304][1024]
  const float* W1w    = (const float*)d_in[1];   // [4096][1024]
  const float* W1b    = (const float*)d_in[2];   // [4096]
  const float* W2w    = (const float*)d_in[3];   // [32000][4096]
  const float* Emb    = (const float*)d_in[4];   // [32000][4096]
  float* out = (float*)d_out;                    // [2304][4096]

  char* ws = (char*)d_ws;
  bf16_t* xn     = (bf16_t*)ws;                             // 18,874,368 B
  bf16_t* logits = (bf16_t*)(ws + 18874368);                // 147,456,000 B
  float*  xbuf   = (float*)(ws + 18874368 + 147456000);     // 37,748,736 B
  bf16_t* wslot  = (bf16_t*)(ws + 18874368 + 147456000 + 37748736); // 262,144,000 B

  const size_t NEED = 18874368ull + 147456000ull + 37748736ull + 262144000ull;

  // 1) x = vision @ W1^T + b   (grid 576)
  gemm_k<1, 0, 0><<<dim3((M_TOK / BM) * (DLAT / BN)), dim3(256), 0, stream>>>(
      vision, W1w, xbuf, W1b, DV, DV, DV, DLAT, M_TOK / BM);

  // 2) xn = LayerNorm(x) -> bf16
  ln_k<<<dim3(M_TOK), dim3(256), 0, stream>>>(xbuf, xn);

  if (ws_size >= NEED) {
    // --- all-bf16 NT path ---
    // 3a) W2 -> bf16 (same [32000][4096] layout)
    cvt_bf16_k<<<dim3(2048), dim3(256), 0, stream>>>(W2w, wslot, (long)VOCAB * DLAT / 8);
    // 3b) logits = xn @ W2b^T -> bf16   (grid 24*250 = 6000)
    gemm_bb<1><<<dim3((M_TOK / GBM) * (VOCAB / GBN)), dim3(256), 0, stream>>>(
        xn, wslot, logits, DLAT, VOCAB, M_TOK / GBM);
    // 4) Emb -> EmbT bf16 [4096][32000] (reuses wslot, W2b dead)
    embT_k<<<dim3((VOCAB / 64) * (DLAT / 64)), dim3(256), 0, stream>>>(Emb, wslot);
    // 5) P = softmax(logits) in place
    softmax_k<<<dim3(M_TOK), dim3(256), 0, stream>>>(logits);
    // 6) out = P @ EmbT^T   (grid 24*32 = 768 = 3/CU exact)
    gemm_bb<2><<<dim3((M_TOK / GBM) * (DLAT / GBN)), dim3(256), 0, stream>>>(
        logits, wslot, out, VOCAB, DLAT, M_TOK / GBM);
  } else {
    // --- fallback: R6 path (f32 B operands) ---
    gemm_k<0, 0, 1><<<dim3((M_TOK / BM) * (VOCAB / BN)), dim3(256), 0, stream>>>(
        xn, W2w, logits, nullptr, DLAT, DLAT, DLAT, VOCAB, M_TOK / BM);
    softmax_k<<<dim3(M_TOK), dim3(256), 0, stream>>>(logits);
    gemm_k<0, 1, 2><<<dim3((M_TOK / BM) * (DLAT / BN)), dim3(256), 0, stream>>>(
        logits, Emb, out, nullptr, VOCAB, VOCAB, DLAT, DLAT, M_TOK / BM);
  }
}

// Round 9
// 1977.813 us; speedup vs baseline: 1.6258x; 1.0795x over previous
//
#include <hip/hip_runtime.h>
#include <hip/hip_bf16.h>
#include <stdint.h>

typedef __bf16 bf16_t;
typedef __attribute__((ext_vector_type(8))) __bf16 bf16x8;
typedef __attribute__((ext_vector_type(4))) __bf16 bf16x4;
typedef __attribute__((ext_vector_type(4))) float f32x4;
typedef __attribute__((ext_vector_type(8))) unsigned short u16x8;

#define M_TOK 2304
#define DV    1024
#define DLAT  4096
#define VOCAB 32000

__device__ __forceinline__ float bf2f(unsigned short u) {
  union { unsigned int i; float f; } v; v.i = ((unsigned int)u) << 16; return v.f;
}
__device__ __forceinline__ bf16_t f2bf(float f) { return (bf16_t)f; }

// async global->LDS, 16B per lane; LDS dest = wave-uniform base + lane*16
#define GLOAD16(gp, lp) \
  __builtin_amdgcn_global_load_lds( \
      (const __attribute__((address_space(1))) unsigned int*)(const void*)(gp), \
      (__attribute__((address_space(3))) unsigned int*)(void*)(lp), 16, 0, 0)

// =============== bf16 x bf16 NT GEMM, counted-vmcnt depth-2 (T3+T4) =========
// A [M][K] bf16 rm, B [N][K] bf16 rm, lda==ldb==K. 128x128 tile, BK=32,
// 3 LDS buffers, raw s_barrier + s_waitcnt vmcnt(4): tile t+2's 4 loads stay
// in flight across the barrier; tile t+1 guaranteed landed.
// EPI: 0 = f32 store + bias, 1 = bf16 store, 2 = f32 store.
constexpr int GBM = 128, GBN = 128, GBK = 32;

template<int EPI>
__global__ void __launch_bounds__(256, 3)
gemm_bb(const bf16_t* __restrict__ Ap, const bf16_t* __restrict__ Bp,
        void* __restrict__ Cp, const float* __restrict__ bias,
        int K, int ldc, int Mt)
{
  __shared__ __align__(16) bf16_t Al[3][GBM * GBK];  // 3 x 8192 B
  __shared__ __align__(16) bf16_t Bl[3][GBN * GBK];  // 3 x 8192 B

  // bijective XCD-chunked swizzle (m204)
  const int nwg = gridDim.x;
  const int orig = blockIdx.x;
  const int q = nwg >> 3, r = nwg & 7;
  const int xcd = orig & 7, idx = orig >> 3;
  const int wg = (xcd < r ? xcd * (q + 1) : r * (q + 1) + (xcd - r) * q) + idx;
  const int mt = wg % Mt, nt = wg / Mt;   // mt fastest: consecutive wg share B panel
  const int m0 = mt * GBM, n0 = nt * GBN;

  const int t    = threadIdx.x;
  const int lane = t & 63, wv = t >> 6;
  const int wm = wv >> 1, wn = wv & 1;     // wave grid 2(M) x 2(N): per-wave 64x64
  const int lr = lane & 15, kc = lane >> 4;

  f32x4 acc[4][4];
#pragma unroll
  for (int i = 0; i < 4; ++i)
#pragma unroll
    for (int j = 0; j < 4; ++j)
#pragma unroll
      for (int x = 0; x < 4; ++x) acc[i][j][x] = 0.0f;

  // staging: each wave stages 32 rows of A and 32 of B; 16 B/lane,
  // 4-lane groups cover one 64 B row (BK=32 bf16). 4 gload_lds per wave/tile.
  const int rql = lane >> 2;
  const int cb  = (lane & 3) * 16;
  const size_t rstride = (size_t)K * 2;

  const int NT = K / GBK;

  auto STAGE = [&](int kt, int nb) {
    const size_t kb = (size_t)kt * GBK * 2;
    const char* ga = (const char*)Ap + (size_t)(m0 + wv * 32 + rql) * rstride + kb + cb;
    char* la = (char*)&Al[nb][0] + wv * 2048;
    GLOAD16(ga, la);
    GLOAD16(ga + 16 * rstride, la + 1024);
    const char* gb = (const char*)Bp + (size_t)(n0 + wv * 32 + rql) * rstride + kb + cb;
    char* lb = (char*)&Bl[nb][0] + wv * 2048;
    GLOAD16(gb, lb);
    GLOAD16(gb + 16 * rstride, lb + 1024);
  };

  auto COMPUTE = [&](int nb) {
    bf16x8 af[4], bfv[4];
#pragma unroll
    for (int f = 0; f < 4; ++f)
      af[f] = *(const bf16x8*)(&Al[nb][(wm * 64 + f * 16 + lr) * GBK + kc * 8]);
#pragma unroll
    for (int f = 0; f < 4; ++f)
      bfv[f] = *(const bf16x8*)(&Bl[nb][(wn * 64 + f * 16 + lr) * GBK + kc * 8]);
    __builtin_amdgcn_s_setprio(1);
#pragma unroll
    for (int i = 0; i < 4; ++i)
#pragma unroll
      for (int j = 0; j < 4; ++j)
        acc[i][j] = __builtin_amdgcn_mfma_f32_16x16x32_bf16(af[i], bfv[j], acc[i][j], 0, 0, 0);
    __builtin_amdgcn_s_setprio(0);
  };

  // barrier with LDS-read drain but NO vmem drain
  auto BARX = [&]() {
    asm volatile("s_waitcnt lgkmcnt(0)" ::: "memory");
    __builtin_amdgcn_s_barrier();
  };

  // prologue: stage tiles 0,1 (8 loads in flight/wave); wait tile0 (vmcnt 4)
  STAGE(0, 0);
  STAGE(1, 1);
  asm volatile("s_waitcnt vmcnt(4)" ::: "memory");
  __builtin_amdgcn_s_barrier();

  int bc = 0, bn = 1, bs = 2;
  for (int kt = 0; kt < NT - 2; ++kt) {
    STAGE(kt + 2, bs);                  // 4 loads fly under COMPUTE + barrier
    COMPUTE(bc);
    asm volatile("s_waitcnt vmcnt(4)" ::: "memory");  // tile kt+1 landed
    BARX();
    const int tmp = bc; bc = bn; bn = bs; bs = tmp;
  }
  // tail: bc = tile NT-2 (ready), bn = tile NT-1 (loads outstanding)
  COMPUTE(bc);
  asm volatile("s_waitcnt vmcnt(0)" ::: "memory");
  BARX();
  COMPUTE(bn);

  // epilogue
#pragma unroll
  for (int j = 0; j < 4; ++j) {
    const int col = n0 + wn * 64 + j * 16 + lr;
    float bv = 0.0f;
    if (EPI == 0) bv = bias[col];
#pragma unroll
    for (int i = 0; i < 4; ++i) {
      const int row = m0 + wm * 64 + i * 16 + kc * 4;
      f32x4 a4 = acc[i][j];
      if (EPI == 1) {
        bf16_t* C = (bf16_t*)Cp;
#pragma unroll
        for (int x = 0; x < 4; ++x) C[(size_t)(row + x) * ldc + col] = f2bf(a4[x]);
      } else {
        float* C = (float*)Cp;
#pragma unroll
        for (int x = 0; x < 4; ++x) C[(size_t)(row + x) * ldc + col] = a4[x] + bv;
      }
    }
  }
}

// ================== generic f32-input GEMM (fallback only) =================
constexpr int BM = 128, BN = 128, BK = 32;
constexpr int SA = 40;

__device__ __forceinline__ void bar_lds() {
  asm volatile("s_waitcnt lgkmcnt(0)" ::: "memory");
  __builtin_amdgcn_s_barrier();
}

template<int AMODE, int BMODE, int EPI>
__global__ void __launch_bounds__(256, 2)
gemm_k(const void* __restrict__ Ap, const float* __restrict__ Bp,
       void* __restrict__ Cp, const float* __restrict__ bias,
       int K, int lda, int ldb, int ldc, int Mt)
{
  __shared__ __align__(16) bf16_t Al[2][BM * SA];
  __shared__ __align__(16) bf16_t Bl[2][BN * SA];

  const int nwg = gridDim.x;
  const int orig = blockIdx.x;
  const int q = nwg >> 3, r = nwg & 7;
  const int xcd = orig & 7, idx = orig >> 3;
  const int wg = (xcd < r ? xcd * (q + 1) : r * (q + 1) + (xcd - r) * q) + idx;
  const int mt = wg % Mt, nt = wg / Mt;
  const int m0 = mt * BM, n0 = nt * BN;

  const int t    = threadIdx.x;
  const int lane = t & 63, wv = t >> 6;
  const int wm = wv >> 1, wn = wv & 1;
  const int lr = lane & 15, kc = lane >> 4;

  f32x4 acc[4][4];
#pragma unroll
  for (int i = 0; i < 4; ++i)
#pragma unroll
    for (int j = 0; j < 4; ++j)
#pragma unroll
      for (int x = 0; x < 4; ++x) acc[i][j][x] = 0.0f;

  const int sr = t >> 1, sh = t & 1;
  const int tv = t & 7, te = t >> 3;

  bf16x8 s1_ab0, s1_ab1;          bf16x8 s2_ab0, s2_ab1;
  f32x4  s1_af0, s1_af1, s1_af2, s1_af3;
  f32x4  s2_af0, s2_af1, s2_af2, s2_af3;
  f32x4  s1_b0, s1_b1, s1_b2, s1_b3;
  f32x4  s2_b0, s2_b1, s2_b2, s2_b3;

  const int NT = K / BK;

  auto LOADS1 = [&](int kt) {
    const int k0 = kt * BK;
    if (AMODE == 0) {
      const bf16_t* asrc = (const bf16_t*)Ap + (size_t)(m0 + sr) * lda + k0 + sh * 16;
      s1_ab0 = *(const bf16x8*)(asrc);
      s1_ab1 = *(const bf16x8*)(asrc + 8);
    } else {
      const float* asrc = (const float*)Ap + (size_t)(m0 + sr) * lda + k0 + sh * 16;
      s1_af0 = *(const f32x4*)(asrc);     s1_af1 = *(const f32x4*)(asrc + 4);
      s1_af2 = *(const f32x4*)(asrc + 8); s1_af3 = *(const f32x4*)(asrc + 12);
    }
    if (BMODE == 0) {
      const float* bsrc = Bp + (size_t)(n0 + sr) * ldb + k0 + sh * 16;
      s1_b0 = *(const f32x4*)(bsrc);     s1_b1 = *(const f32x4*)(bsrc + 4);
      s1_b2 = *(const f32x4*)(bsrc + 8); s1_b3 = *(const f32x4*)(bsrc + 12);
    } else {
      const float* bsrc = Bp + (size_t)(k0 + tv * 4) * ldb + n0 + te * 4;
      s1_b0 = *(const f32x4*)(bsrc);
      s1_b1 = *(const f32x4*)(bsrc + (size_t)ldb);
      s1_b2 = *(const f32x4*)(bsrc + (size_t)2 * ldb);
      s1_b3 = *(const f32x4*)(bsrc + (size_t)3 * ldb);
    }
  };
  auto LOADS2 = [&](int kt) {
    const int k0 = kt * BK;
    if (AMODE == 0) {
      const bf16_t* asrc = (const bf16_t*)Ap + (size_t)(m0 + sr) * lda + k0 + sh * 16;
      s2_ab0 = *(const bf16x8*)(asrc);
      s2_ab1 = *(const bf16x8*)(asrc + 8);
    } else {
      const float* asrc = (const float*)Ap + (size_t)(m0 + sr) * lda + k0 + sh * 16;
      s2_af0 = *(const f32x4*)(asrc);     s2_af1 = *(const f32x4*)(asrc + 4);
      s2_af2 = *(const f32x4*)(asrc + 8); s2_af3 = *(const f32x4*)(asrc + 12);
    }
    if (BMODE == 0) {
      const float* bsrc = Bp + (size_t)(n0 + sr) * ldb + k0 + sh * 16;
      s2_b0 = *(const f32x4*)(bsrc);     s2_b1 = *(const f32x4*)(bsrc + 4);
      s2_b2 = *(const f32x4*)(bsrc + 8); s2_b3 = *(const f32x4*)(bsrc + 12);
    } else {
      const float* bsrc = Bp + (size_t)(k0 + tv * 4) * ldb + n0 + te * 4;
      s2_b0 = *(const f32x4*)(bsrc);
      s2_b1 = *(const f32x4*)(bsrc + (size_t)ldb);
      s2_b2 = *(const f32x4*)(bsrc + (size_t)2 * ldb);
      s2_b3 = *(const f32x4*)(bsrc + (size_t)3 * ldb);
    }
  };

  auto STORE1 = [&](int nb) {
    {
      bf16x8 w0, w1;
      if (AMODE == 0) { w0 = s1_ab0; w1 = s1_ab1; }
      else {
#pragma unroll
        for (int c = 0; c < 4; ++c) {
          w0[c] = f2bf(s1_af0[c]); w0[c + 4] = f2bf(s1_af1[c]);
          w1[c] = f2bf(s1_af2[c]); w1[c + 4] = f2bf(s1_af3[c]);
        }
      }
      bf16_t* dst = &Al[nb][sr * SA + sh * 16];
      *(bf16x8*)(dst) = w0; *(bf16x8*)(dst + 8) = w1;
    }
    if (BMODE == 0) {
      bf16x8 w0, w1;
#pragma unroll
      for (int c = 0; c < 4; ++c) {
        w0[c] = f2bf(s1_b0[c]); w0[c + 4] = f2bf(s1_b1[c]);
        w1[c] = f2bf(s1_b2[c]); w1[c + 4] = f2bf(s1_b3[c]);
      }
      bf16_t* dst = &Bl[nb][sr * SA + sh * 16];
      *(bf16x8*)(dst) = w0; *(bf16x8*)(dst + 8) = w1;
    } else {
#pragma unroll
      for (int i = 0; i < 4; ++i) {
        bf16x4 w4;
        w4[0] = f2bf(s1_b0[i]); w4[1] = f2bf(s1_b1[i]);
        w4[2] = f2bf(s1_b2[i]); w4[3] = f2bf(s1_b3[i]);
        *(bf16x4*)(&Bl[nb][(te * 4 + i) * SA + tv * 4]) = w4;
      }
    }
  };
  auto STORE2 = [&](int nb) {
    {
      bf16x8 w0, w1;
      if (AMODE == 0) { w0 = s2_ab0; w1 = s2_ab1; }
      else {
#pragma unroll
        for (int c = 0; c < 4; ++c) {
          w0[c] = f2bf(s2_af0[c]); w0[c + 4] = f2bf(s2_af1[c]);
          w1[c] = f2bf(s2_af2[c]); w1[c + 4] = f2bf(s2_af3[c]);
        }
      }
      bf16_t* dst = &Al[nb][sr * SA + sh * 16];
      *(bf16x8*)(dst) = w0; *(bf16x8*)(dst + 8) = w1;
    }
    if (BMODE == 0) {
      bf16x8 w0, w1;
#pragma unroll
      for (int c = 0; c < 4; ++c) {
        w0[c] = f2bf(s2_b0[c]); w0[c + 4] = f2bf(s2_b1[c]);
        w1[c] = f2bf(s2_b2[c]); w1[c + 4] = f2bf(s2_b3[c]);
      }
      bf16_t* dst = &Bl[nb][sr * SA + sh * 16];
      *(bf16x8*)(dst) = w0; *(bf16x8*)(dst + 8) = w1;
    } else {
#pragma unroll
      for (int i = 0; i < 4; ++i) {
        bf16x4 w4;
        w4[0] = f2bf(s2_b0[i]); w4[1] = f2bf(s2_b1[i]);
        w4[2] = f2bf(s2_b2[i]); w4[3] = f2bf(s2_b3[i]);
        *(bf16x4*)(&Bl[nb][(te * 4 + i) * SA + tv * 4]) = w4;
      }
    }
  };

  auto COMPUTE = [&](int nb) {
    bf16x8 af[4], bfv[4];
#pragma unroll
    for (int f = 0; f < 4; ++f)
      af[f] = *(const bf16x8*)(&Al[nb][(wm * 64 + f * 16 + lr) * SA + kc * 8]);
#pragma unroll
    for (int f = 0; f < 4; ++f)
      bfv[f] = *(const bf16x8*)(&Bl[nb][(wn * 64 + f * 16 + lr) * SA + kc * 8]);
    __builtin_amdgcn_s_setprio(1);
#pragma unroll
    for (int i = 0; i < 4; ++i)
#pragma unroll
      for (int j = 0; j < 4; ++j)
        acc[i][j] = __builtin_amdgcn_mfma_f32_16x16x32_bf16(af[i], bfv[j], acc[i][j], 0, 0, 0);
    __builtin_amdgcn_s_setprio(0);
  };

  LOADS1(0);
  LOADS2(1);
  STORE1(0);
  bar_lds();

  const int NIT = NT / 2 - 1;
  for (int it = 0; it < NIT; ++it) {
    LOADS1(2 * it + 2);
    COMPUTE(0);
    STORE2(1);
    bar_lds();
    LOADS2(2 * it + 3);
    COMPUTE(1);
    STORE1(0);
    bar_lds();
  }
  COMPUTE(0);
  STORE2(1);
  bar_lds();
  COMPUTE(1);

#pragma unroll
  for (int j = 0; j < 4; ++j) {
    const int col = n0 + wn * 64 + j * 16 + lr;
    float bv = 0.0f;
    if (EPI == 0) bv = bias[col];
#pragma unroll
    for (int i = 0; i < 4; ++i) {
      const int row = m0 + wm * 64 + i * 16 + kc * 4;
      f32x4 a4 = acc[i][j];
      if (EPI == 0) {
        float* C = (float*)Cp;
#pragma unroll
        for (int x = 0; x < 4; ++x) C[(size_t)(row + x) * ldc + col] = a4[x] + bv;
      } else if (EPI == 1) {
        bf16_t* C = (bf16_t*)Cp;
#pragma unroll
        for (int x = 0; x < 4; ++x) C[(size_t)(row + x) * ldc + col] = f2bf(a4[x]);
      } else {
        float* C = (float*)Cp;
#pragma unroll
        for (int x = 0; x < 4; ++x) C[(size_t)(row + x) * ldc + col] = a4[x];
      }
    }
  }
}

// -------- stream convert f32 -> bf16 (same layout) --------
__global__ void __launch_bounds__(256)
cvt_bf16_k(const float* __restrict__ in, bf16_t* __restrict__ out, long n8)
{
  const long stride = (long)gridDim.x * 256;
  for (long i = (long)blockIdx.x * 256 + threadIdx.x; i < n8; i += stride) {
    f32x4 a = *(const f32x4*)(in + i * 8);
    f32x4 b = *(const f32x4*)(in + i * 8 + 4);
    bf16x8 o;
#pragma unroll
    for (int j = 0; j < 4; ++j) { o[j] = f2bf(a[j]); o[j + 4] = f2bf(b[j]); }
    *(bf16x8*)(out + i * 8) = o;
  }
}

// -------- Emb [32000][4096] f32  ->  EmbT [4096][32000] bf16 (LDS-tiled) ----
__global__ void __launch_bounds__(256)
embT_k(const float* __restrict__ E, bf16_t* __restrict__ ET)
{
  __shared__ bf16_t tl[64][72];
  const int vb = blockIdx.x % (VOCAB / 64);
  const int eb = blockIdx.x / (VOCAB / 64);
  const int v0 = vb * 64, e0 = eb * 64;
  const int t = threadIdx.x;

  const int rr = t >> 4, c4 = (t & 15) * 4;
#pragma unroll
  for (int p = 0; p < 4; ++p) {
    const float* src = E + (size_t)(v0 + rr + p * 16) * DLAT + e0 + c4;
    f32x4 a = *(const f32x4*)src;
#pragma unroll
    for (int j = 0; j < 4; ++j) tl[c4 + j][rr + p * 16] = f2bf(a[j]);
  }
  __syncthreads();

  const int el = t >> 3, v8 = (t & 7) * 8;
#pragma unroll
  for (int p = 0; p < 2; ++p) {
    bf16x8 o = *(const bf16x8*)(&tl[el + p * 32][v8]);
    *(bf16x8*)(ET + (size_t)(e0 + el + p * 32) * VOCAB + v0 + v8) = o;
  }
}

// -------- LayerNorm over last dim (4096), f32 in -> bf16 out --------
__global__ void __launch_bounds__(256)
ln_k(const float* __restrict__ x, bf16_t* __restrict__ xn)
{
  __shared__ float sm[4];
  const int row = blockIdx.x, t = threadIdx.x;
  const float* xr = x + (size_t)row * DLAT;
  f32x4 v[4];
#pragma unroll
  for (int i = 0; i < 4; ++i) v[i] = *(const f32x4*)(xr + (t + i * 256) * 4);

  float s = 0.0f;
#pragma unroll
  for (int i = 0; i < 4; ++i)
#pragma unroll
    for (int j = 0; j < 4; ++j) s += v[i][j];
#pragma unroll
  for (int o = 32; o > 0; o >>= 1) s += __shfl_xor(s, o, 64);
  if ((t & 63) == 0) sm[t >> 6] = s;
  __syncthreads();
  const float mean = (sm[0] + sm[1] + sm[2] + sm[3]) * (1.0f / DLAT);
  __syncthreads();

  float qv = 0.0f;
#pragma unroll
  for (int i = 0; i < 4; ++i)
#pragma unroll
    for (int j = 0; j < 4; ++j) { float d = v[i][j] - mean; qv += d * d; }
#pragma unroll
  for (int o = 32; o > 0; o >>= 1) qv += __shfl_xor(qv, o, 64);
  if ((t & 63) == 0) sm[t >> 6] = qv;
  __syncthreads();
  const float varr = (sm[0] + sm[1] + sm[2] + sm[3]) * (1.0f / DLAT);
  const float rs = rsqrtf(varr + 1e-5f);

  bf16_t* outr = xn + (size_t)row * DLAT;
#pragma unroll
  for (int i = 0; i < 4; ++i) {
    bf16x4 o;
#pragma unroll
    for (int j = 0; j < 4; ++j) o[j] = f2bf((v[i][j] - mean) * rs);
    *(bf16x4*)(outr + (t + i * 256) * 4) = o;
  }
}

// -------- row softmax over V=32000, bf16 in-place, row staged in LDS --------
__global__ void __launch_bounds__(256)
softmax_k(bf16_t* __restrict__ L)
{
  __shared__ __align__(16) bf16_t rs_[VOCAB];
  __shared__ float sm[4];
  const int row = blockIdx.x, t = threadIdx.x;
  bf16_t* lrow = L + (size_t)row * VOCAB;
  const int NF = VOCAB / 8;

  float m = -3.0e38f;
  for (int f = t; f < NF; f += 256) {
    u16x8 u = *(const u16x8*)(&lrow[f * 8]);
    *(u16x8*)(&rs_[f * 8]) = u;
#pragma unroll
    for (int j = 0; j < 8; ++j) m = fmaxf(m, bf2f(u[j]));
  }
#pragma unroll
  for (int o = 32; o > 0; o >>= 1) m = fmaxf(m, __shfl_xor(m, o, 64));
  if ((t & 63) == 0) sm[t >> 6] = m;
  __syncthreads();
  m = fmaxf(fmaxf(sm[0], sm[1]), fmaxf(sm[2], sm[3]));
  __syncthreads();

  float s = 0.0f;
  for (int f = t; f < NF; f += 256) {
    u16x8 u = *(const u16x8*)(&rs_[f * 8]);
#pragma unroll
    for (int j = 0; j < 8; ++j) s += __expf(bf2f(u[j]) - m);
  }
#pragma unroll
  for (int o = 32; o > 0; o >>= 1) s += __shfl_xor(s, o, 64);
  if ((t & 63) == 0) sm[t >> 6] = s;
  __syncthreads();
  const float inv = 1.0f / (sm[0] + sm[1] + sm[2] + sm[3]);

  for (int f = t; f < NF; f += 256) {
    u16x8 u = *(const u16x8*)(&rs_[f * 8]);
    bf16x8 o;
#pragma unroll
    for (int j = 0; j < 8; ++j) o[j] = f2bf(__expf(bf2f(u[j]) - m) * inv);
    *(bf16x8*)(&lrow[f * 8]) = o;
  }
}

extern "C" void kernel_launch(void* const* d_in, const int* in_sizes, int n_in,
                              void* d_out, int out_size, void* d_ws, size_t ws_size,
                              hipStream_t stream)
{
  (void)in_sizes; (void)n_in; (void)out_size;
  const float* vision = (const float*)d_in[0];   // [2304][1024]
  const float* W1w    = (const float*)d_in[1];   // [4096][1024]
  const float* W1b    = (const float*)d_in[2];   // [4096]
  const float* W2w    = (const float*)d_in[3];   // [32000][4096]
  const float* Emb    = (const float*)d_in[4];   // [32000][4096]
  float* out = (float*)d_out;                    // [2304][4096]

  char* ws = (char*)d_ws;
  bf16_t* xn     = (bf16_t*)ws;                              //  18,874,368
  bf16_t* logits = (bf16_t*)(ws + 18874368);                 // 147,456,000
  float*  xbuf   = (float*)(ws + 166330368);                 //  37,748,736
  bf16_t* wslot  = (bf16_t*)(ws + 204079104);                // 262,144,000
  bf16_t* xnv    = (bf16_t*)(ws + 466223104);                //   4,718,592
  bf16_t* w1b    = (bf16_t*)(ws + 470941696);                //   8,388,608
  const size_t NEED = 479330304ull;

  const int Mt = M_TOK / GBM;  // 18

  if (ws_size >= NEED) {
    // 0) convert vision + W1 to bf16
    cvt_bf16_k<<<dim3(512), dim3(256), 0, stream>>>(vision, xnv, (long)M_TOK * DV / 8);
    cvt_bf16_k<<<dim3(512), dim3(256), 0, stream>>>(W1w, w1b, (long)DLAT * DV / 8);
    // 1) x = vision @ W1^T + b   (grid 18*32 = 576, all co-resident)
    gemm_bb<0><<<dim3(Mt * (DLAT / GBN)), dim3(256), 0, stream>>>(
        xnv, w1b, xbuf, W1b, DV, DLAT, Mt);
    // 2) xn = LayerNorm(x) -> bf16
    ln_k<<<dim3(M_TOK), dim3(256), 0, stream>>>(xbuf, xn);
    // 3a) W2 -> bf16
    cvt_bf16_k<<<dim3(2048), dim3(256), 0, stream>>>(W2w, wslot, (long)VOCAB * DLAT / 8);
    // 3b) logits = xn @ W2b^T -> bf16   (grid 18*250 = 4500)
    gemm_bb<1><<<dim3(Mt * (VOCAB / GBN)), dim3(256), 0, stream>>>(
        xn, wslot, logits, nullptr, DLAT, VOCAB, Mt);
    // 4) Emb -> EmbT bf16 [4096][32000] (reuses wslot)
    embT_k<<<dim3((VOCAB / 64) * (DLAT / 64)), dim3(256), 0, stream>>>(Emb, wslot);
    // 5) P = softmax(logits) in place
    softmax_k<<<dim3(M_TOK), dim3(256), 0, stream>>>(logits);
    // 6) out = P @ EmbT^T   (grid 576, all co-resident)
    gemm_bb<2><<<dim3(Mt * (DLAT / GBN)), dim3(256), 0, stream>>>(
        logits, wslot, out, nullptr, VOCAB, DLAT, Mt);
  } else {
    // --- fallback: R6 path ---
    gemm_k<1, 0, 0><<<dim3((M_TOK / BM) * (DLAT / BN)), dim3(256), 0, stream>>>(
        vision, W1w, xbuf, W1b, DV, DV, DV, DLAT, M_TOK / BM);
    ln_k<<<dim3(M_TOK), dim3(256), 0, stream>>>(xbuf, xn);
    gemm_k<0, 0, 1><<<dim3((M_TOK / BM) * (VOCAB / BN)), dim3(256), 0, stream>>>(
        xn, W2w, logits, nullptr, DLAT, DLAT, DLAT, VOCAB, M_TOK / BM);
    softmax_k<<<dim3(M_TOK), dim3(256), 0, stream>>>(logits);
    gemm_k<0, 1, 2><<<dim3((M_TOK / BM) * (DLAT / BN)), dim3(256), 0, stream>>>(
        logits, Emb, out, nullptr, VOCAB, VOCAB, DLAT, DLAT, M_TOK / BM);
  }
}

// Round 10
// 1954.694 us; speedup vs baseline: 1.6450x; 1.0118x over previous
//
#include <hip/hip_runtime.h>
#include <hip/hip_bf16.h>
#include <stdint.h>

typedef __bf16 bf16_t;
typedef __attribute__((ext_vector_type(8))) __bf16 bf16x8;
typedef __attribute__((ext_vector_type(4))) __bf16 bf16x4;
typedef __attribute__((ext_vector_type(4))) float f32x4;
typedef __attribute__((ext_vector_type(8))) unsigned short u16x8;

#define M_TOK 2304
#define DV    1024
#define DLAT  4096
#define VOCAB 32000

__device__ __forceinline__ float bf2f(unsigned short u) {
  union { unsigned int i; float f; } v; v.i = ((unsigned int)u) << 16; return v.f;
}
__device__ __forceinline__ bf16_t f2bf(float f) { return (bf16_t)f; }

// async global->LDS, 16B per lane; LDS dest = wave-uniform base + lane*16
#define GLOAD16(gp, lp) \
  __builtin_amdgcn_global_load_lds( \
      (const __attribute__((address_space(1))) unsigned int*)(const void*)(gp), \
      (__attribute__((address_space(3))) unsigned int*)(void*)(lp), 16, 0, 0)

// =============== bf16 x bf16 NT GEMM, counted-vmcnt depth-2 + T2 swizzle ====
// A [M][K] bf16 rm, B [N][K] bf16 rm, lda==ldb==K. 128x128 tile, BK=32,
// 3 LDS buffers. Bank-conflict fix (rule #21 both-sides swizzle): LDS dest
// stays linear (gload_lds requires it); the per-lane GLOBAL source column is
// pre-swizzled, and fragment reads apply the same XOR:
//   granule (row, slot) stored at slot' = slot ^ ((row>>1)&3)
// -> 16-lane frag-read groups go 8-way -> 2-way (free).
// EPI: 0 = f32 store + bias, 1 = bf16 store, 2 = f32 store.
constexpr int GBM = 128, GBN = 128, GBK = 32;

template<int EPI>
__global__ void __launch_bounds__(256, 3)
gemm_bb(const bf16_t* __restrict__ Ap, const bf16_t* __restrict__ Bp,
        void* __restrict__ Cp, const float* __restrict__ bias,
        int K, int ldc, int Mt)
{
  __shared__ __align__(16) bf16_t Al[3][GBM * GBK];  // 3 x 8192 B
  __shared__ __align__(16) bf16_t Bl[3][GBN * GBK];  // 3 x 8192 B

  // bijective XCD-chunked swizzle (m204)
  const int nwg = gridDim.x;
  const int orig = blockIdx.x;
  const int q = nwg >> 3, r = nwg & 7;
  const int xcd = orig & 7, idx = orig >> 3;
  const int wg = (xcd < r ? xcd * (q + 1) : r * (q + 1) + (xcd - r) * q) + idx;
  const int mt = wg % Mt, nt = wg / Mt;   // mt fastest: consecutive wg share B panel
  const int m0 = mt * GBM, n0 = nt * GBN;

  const int t    = threadIdx.x;
  const int lane = t & 63, wv = t >> 6;
  const int wm = wv >> 1, wn = wv & 1;     // wave grid 2(M) x 2(N): per-wave 64x64
  const int lr = lane & 15, kc = lane >> 4;

  f32x4 acc[4][4];
#pragma unroll
  for (int i = 0; i < 4; ++i)
#pragma unroll
    for (int j = 0; j < 4; ++j)
#pragma unroll
      for (int x = 0; x < 4; ++x) acc[i][j][x] = 0.0f;

  // staging: wave stages 32 rows of A and B (16 B/lane, 2 gloads each).
  // Global source column is swizzle-permuted (write side of rule #21).
  const int rql = lane >> 2;
  const int cbs = (((lane & 3) ^ ((lane >> 3) & 3)) * 16);  // swizzled col byte
  const size_t rstride = (size_t)K * 2;

  // read-side swizzle: slot' = kc ^ ((row>>1)&3); row = f*16+lr -> (lr>>1)&3
  const int sw8 = (kc ^ ((lr >> 1) & 3)) * 8;   // bf16 units

  const int NT = K / GBK;

  auto STAGE = [&](int kt, int nb) {
    const size_t kb = (size_t)kt * GBK * 2;
    const char* ga = (const char*)Ap + (size_t)(m0 + wv * 32 + rql) * rstride + kb + cbs;
    char* la = (char*)&Al[nb][0] + wv * 2048;
    GLOAD16(ga, la);
    GLOAD16(ga + 16 * rstride, la + 1024);
    const char* gb = (const char*)Bp + (size_t)(n0 + wv * 32 + rql) * rstride + kb + cbs;
    char* lb = (char*)&Bl[nb][0] + wv * 2048;
    GLOAD16(gb, lb);
    GLOAD16(gb + 16 * rstride, lb + 1024);
  };

  auto COMPUTE = [&](int nb) {
    bf16x8 af[4], bfv[4];
#pragma unroll
    for (int f = 0; f < 4; ++f)
      af[f] = *(const bf16x8*)(&Al[nb][(wm * 64 + f * 16 + lr) * GBK + sw8]);
#pragma unroll
    for (int f = 0; f < 4; ++f)
      bfv[f] = *(const bf16x8*)(&Bl[nb][(wn * 64 + f * 16 + lr) * GBK + sw8]);
    __builtin_amdgcn_s_setprio(1);
#pragma unroll
    for (int i = 0; i < 4; ++i)
#pragma unroll
      for (int j = 0; j < 4; ++j)
        acc[i][j] = __builtin_amdgcn_mfma_f32_16x16x32_bf16(af[i], bfv[j], acc[i][j], 0, 0, 0);
    __builtin_amdgcn_s_setprio(0);
  };

  auto BARX = [&]() {
    asm volatile("s_waitcnt lgkmcnt(0)" ::: "memory");
    __builtin_amdgcn_s_barrier();
  };

  // prologue: stage tiles 0,1 (8 loads/wave in flight); wait tile0 only
  STAGE(0, 0);
  STAGE(1, 1);
  asm volatile("s_waitcnt vmcnt(4)" ::: "memory");
  __builtin_amdgcn_s_barrier();

  int bc = 0, bn = 1, bs = 2;
  for (int kt = 0; kt < NT - 2; ++kt) {
    STAGE(kt + 2, bs);                  // 4 loads fly under COMPUTE + barrier
    COMPUTE(bc);
    asm volatile("s_waitcnt vmcnt(4)" ::: "memory");  // tile kt+1 landed
    BARX();
    const int tmp = bc; bc = bn; bn = bs; bs = tmp;
  }
  COMPUTE(bc);
  asm volatile("s_waitcnt vmcnt(0)" ::: "memory");
  BARX();
  COMPUTE(bn);

  // epilogue
#pragma unroll
  for (int j = 0; j < 4; ++j) {
    const int col = n0 + wn * 64 + j * 16 + lr;
    float bv = 0.0f;
    if (EPI == 0) bv = bias[col];
#pragma unroll
    for (int i = 0; i < 4; ++i) {
      const int row = m0 + wm * 64 + i * 16 + kc * 4;
      f32x4 a4 = acc[i][j];
      if (EPI == 1) {
        bf16_t* C = (bf16_t*)Cp;
#pragma unroll
        for (int x = 0; x < 4; ++x) C[(size_t)(row + x) * ldc + col] = f2bf(a4[x]);
      } else {
        float* C = (float*)Cp;
#pragma unroll
        for (int x = 0; x < 4; ++x) C[(size_t)(row + x) * ldc + col] = a4[x] + bv;
      }
    }
  }
}

// ================== generic f32-input GEMM (fallback only) =================
constexpr int BM = 128, BN = 128, BK = 32;
constexpr int SA = 40;

__device__ __forceinline__ void bar_lds() {
  asm volatile("s_waitcnt lgkmcnt(0)" ::: "memory");
  __builtin_amdgcn_s_barrier();
}

template<int AMODE, int BMODE, int EPI>
__global__ void __launch_bounds__(256, 2)
gemm_k(const void* __restrict__ Ap, const float* __restrict__ Bp,
       void* __restrict__ Cp, const float* __restrict__ bias,
       int K, int lda, int ldb, int ldc, int Mt)
{
  __shared__ __align__(16) bf16_t Al[2][BM * SA];
  __shared__ __align__(16) bf16_t Bl[2][BN * SA];

  const int nwg = gridDim.x;
  const int orig = blockIdx.x;
  const int q = nwg >> 3, r = nwg & 7;
  const int xcd = orig & 7, idx = orig >> 3;
  const int wg = (xcd < r ? xcd * (q + 1) : r * (q + 1) + (xcd - r) * q) + idx;
  const int mt = wg % Mt, nt = wg / Mt;
  const int m0 = mt * BM, n0 = nt * BN;

  const int t    = threadIdx.x;
  const int lane = t & 63, wv = t >> 6;
  const int wm = wv >> 1, wn = wv & 1;
  const int lr = lane & 15, kc = lane >> 4;

  f32x4 acc[4][4];
#pragma unroll
  for (int i = 0; i < 4; ++i)
#pragma unroll
    for (int j = 0; j < 4; ++j)
#pragma unroll
      for (int x = 0; x < 4; ++x) acc[i][j][x] = 0.0f;

  const int sr = t >> 1, sh = t & 1;
  const int tv = t & 7, te = t >> 3;

  bf16x8 s1_ab0, s1_ab1;          bf16x8 s2_ab0, s2_ab1;
  f32x4  s1_af0, s1_af1, s1_af2, s1_af3;
  f32x4  s2_af0, s2_af1, s2_af2, s2_af3;
  f32x4  s1_b0, s1_b1, s1_b2, s1_b3;
  f32x4  s2_b0, s2_b1, s2_b2, s2_b3;

  const int NT = K / BK;

  auto LOADS1 = [&](int kt) {
    const int k0 = kt * BK;
    if (AMODE == 0) {
      const bf16_t* asrc = (const bf16_t*)Ap + (size_t)(m0 + sr) * lda + k0 + sh * 16;
      s1_ab0 = *(const bf16x8*)(asrc);
      s1_ab1 = *(const bf16x8*)(asrc + 8);
    } else {
      const float* asrc = (const float*)Ap + (size_t)(m0 + sr) * lda + k0 + sh * 16;
      s1_af0 = *(const f32x4*)(asrc);     s1_af1 = *(const f32x4*)(asrc + 4);
      s1_af2 = *(const f32x4*)(asrc + 8); s1_af3 = *(const f32x4*)(asrc + 12);
    }
    if (BMODE == 0) {
      const float* bsrc = Bp + (size_t)(n0 + sr) * ldb + k0 + sh * 16;
      s1_b0 = *(const f32x4*)(bsrc);     s1_b1 = *(const f32x4*)(bsrc + 4);
      s1_b2 = *(const f32x4*)(bsrc + 8); s1_b3 = *(const f32x4*)(bsrc + 12);
    } else {
      const float* bsrc = Bp + (size_t)(k0 + tv * 4) * ldb + n0 + te * 4;
      s1_b0 = *(const f32x4*)(bsrc);
      s1_b1 = *(const f32x4*)(bsrc + (size_t)ldb);
      s1_b2 = *(const f32x4*)(bsrc + (size_t)2 * ldb);
      s1_b3 = *(const f32x4*)(bsrc + (size_t)3 * ldb);
    }
  };
  auto LOADS2 = [&](int kt) {
    const int k0 = kt * BK;
    if (AMODE == 0) {
      const bf16_t* asrc = (const bf16_t*)Ap + (size_t)(m0 + sr) * lda + k0 + sh * 16;
      s2_ab0 = *(const bf16x8*)(asrc);
      s2_ab1 = *(const bf16x8*)(asrc + 8);
    } else {
      const float* asrc = (const float*)Ap + (size_t)(m0 + sr) * lda + k0 + sh * 16;
      s2_af0 = *(const f32x4*)(asrc);     s2_af1 = *(const f32x4*)(asrc + 4);
      s2_af2 = *(const f32x4*)(asrc + 8); s2_af3 = *(const f32x4*)(asrc + 12);
    }
    if (BMODE == 0) {
      const float* bsrc = Bp + (size_t)(n0 + sr) * ldb + k0 + sh * 16;
      s2_b0 = *(const f32x4*)(bsrc);     s2_b1 = *(const f32x4*)(bsrc + 4);
      s2_b2 = *(const f32x4*)(bsrc + 8); s2_b3 = *(const f32x4*)(bsrc + 12);
    } else {
      const float* bsrc = Bp + (size_t)(k0 + tv * 4) * ldb + n0 + te * 4;
      s2_b0 = *(const f32x4*)(bsrc);
      s2_b1 = *(const f32x4*)(bsrc + (size_t)ldb);
      s2_b2 = *(const f32x4*)(bsrc + (size_t)2 * ldb);
      s2_b3 = *(const f32x4*)(bsrc + (size_t)3 * ldb);
    }
  };

  auto STORE1 = [&](int nb) {
    {
      bf16x8 w0, w1;
      if (AMODE == 0) { w0 = s1_ab0; w1 = s1_ab1; }
      else {
#pragma unroll
        for (int c = 0; c < 4; ++c) {
          w0[c] = f2bf(s1_af0[c]); w0[c + 4] = f2bf(s1_af1[c]);
          w1[c] = f2bf(s1_af2[c]); w1[c + 4] = f2bf(s1_af3[c]);
        }
      }
      bf16_t* dst = &Al[nb][sr * SA + sh * 16];
      *(bf16x8*)(dst) = w0; *(bf16x8*)(dst + 8) = w1;
    }
    if (BMODE == 0) {
      bf16x8 w0, w1;
#pragma unroll
      for (int c = 0; c < 4; ++c) {
        w0[c] = f2bf(s1_b0[c]); w0[c + 4] = f2bf(s1_b1[c]);
        w1[c] = f2bf(s1_b2[c]); w1[c + 4] = f2bf(s1_b3[c]);
      }
      bf16_t* dst = &Bl[nb][sr * SA + sh * 16];
      *(bf16x8*)(dst) = w0; *(bf16x8*)(dst + 8) = w1;
    } else {
#pragma unroll
      for (int i = 0; i < 4; ++i) {
        bf16x4 w4;
        w4[0] = f2bf(s1_b0[i]); w4[1] = f2bf(s1_b1[i]);
        w4[2] = f2bf(s1_b2[i]); w4[3] = f2bf(s1_b3[i]);
        *(bf16x4*)(&Bl[nb][(te * 4 + i) * SA + tv * 4]) = w4;
      }
    }
  };
  auto STORE2 = [&](int nb) {
    {
      bf16x8 w0, w1;
      if (AMODE == 0) { w0 = s2_ab0; w1 = s2_ab1; }
      else {
#pragma unroll
        for (int c = 0; c < 4; ++c) {
          w0[c] = f2bf(s2_af0[c]); w0[c + 4] = f2bf(s2_af1[c]);
          w1[c] = f2bf(s2_af2[c]); w1[c + 4] = f2bf(s2_af3[c]);
        }
      }
      bf16_t* dst = &Al[nb][sr * SA + sh * 16];
      *(bf16x8*)(dst) = w0; *(bf16x8*)(dst + 8) = w1;
    }
    if (BMODE == 0) {
      bf16x8 w0, w1;
#pragma unroll
      for (int c = 0; c < 4; ++c) {
        w0[c] = f2bf(s2_b0[c]); w0[c + 4] = f2bf(s2_b1[c]);
        w1[c] = f2bf(s2_b2[c]); w1[c + 4] = f2bf(s2_b3[c]);
      }
      bf16_t* dst = &Bl[nb][sr * SA + sh * 16];
      *(bf16x8*)(dst) = w0; *(bf16x8*)(dst + 8) = w1;
    } else {
#pragma unroll
      for (int i = 0; i < 4; ++i) {
        bf16x4 w4;
        w4[0] = f2bf(s2_b0[i]); w4[1] = f2bf(s2_b1[i]);
        w4[2] = f2bf(s2_b2[i]); w4[3] = f2bf(s2_b3[i]);
        *(bf16x4*)(&Bl[nb][(te * 4 + i) * SA + tv * 4]) = w4;
      }
    }
  };

  auto COMPUTE = [&](int nb) {
    bf16x8 af[4], bfv[4];
#pragma unroll
    for (int f = 0; f < 4; ++f)
      af[f] = *(const bf16x8*)(&Al[nb][(wm * 64 + f * 16 + lr) * SA + kc * 8]);
#pragma unroll
    for (int f = 0; f < 4; ++f)
      bfv[f] = *(const bf16x8*)(&Bl[nb][(wn * 64 + f * 16 + lr) * SA + kc * 8]);
    __builtin_amdgcn_s_setprio(1);
#pragma unroll
    for (int i = 0; i < 4; ++i)
#pragma unroll
      for (int j = 0; j < 4; ++j)
        acc[i][j] = __builtin_amdgcn_mfma_f32_16x16x32_bf16(af[i], bfv[j], acc[i][j], 0, 0, 0);
    __builtin_amdgcn_s_setprio(0);
  };

  LOADS1(0);
  LOADS2(1);
  STORE1(0);
  bar_lds();

  const int NIT = NT / 2 - 1;
  for (int it = 0; it < NIT; ++it) {
    LOADS1(2 * it + 2);
    COMPUTE(0);
    STORE2(1);
    bar_lds();
    LOADS2(2 * it + 3);
    COMPUTE(1);
    STORE1(0);
    bar_lds();
  }
  COMPUTE(0);
  STORE2(1);
  bar_lds();
  COMPUTE(1);

#pragma unroll
  for (int j = 0; j < 4; ++j) {
    const int col = n0 + wn * 64 + j * 16 + lr;
    float bv = 0.0f;
    if (EPI == 0) bv = bias[col];
#pragma unroll
    for (int i = 0; i < 4; ++i) {
      const int row = m0 + wm * 64 + i * 16 + kc * 4;
      f32x4 a4 = acc[i][j];
      if (EPI == 0) {
        float* C = (float*)Cp;
#pragma unroll
        for (int x = 0; x < 4; ++x) C[(size_t)(row + x) * ldc + col] = a4[x] + bv;
      } else if (EPI == 1) {
        bf16_t* C = (bf16_t*)Cp;
#pragma unroll
        for (int x = 0; x < 4; ++x) C[(size_t)(row + x) * ldc + col] = f2bf(a4[x]);
      } else {
        float* C = (float*)Cp;
#pragma unroll
        for (int x = 0; x < 4; ++x) C[(size_t)(row + x) * ldc + col] = a4[x];
      }
    }
  }
}

// -------- stream convert f32 -> bf16 (same layout) --------
__global__ void __launch_bounds__(256)
cvt_bf16_k(const float* __restrict__ in, bf16_t* __restrict__ out, long n8)
{
  const long stride = (long)gridDim.x * 256;
  for (long i = (long)blockIdx.x * 256 + threadIdx.x; i < n8; i += stride) {
    f32x4 a = *(const f32x4*)(in + i * 8);
    f32x4 b = *(const f32x4*)(in + i * 8 + 4);
    bf16x8 o;
#pragma unroll
    for (int j = 0; j < 4; ++j) { o[j] = f2bf(a[j]); o[j + 4] = f2bf(b[j]); }
    *(bf16x8*)(out + i * 8) = o;
  }
}

// -------- Emb [32000][4096] f32  ->  EmbT [4096][32000] bf16 (LDS-tiled) ----
__global__ void __launch_bounds__(256)
embT_k(const float* __restrict__ E, bf16_t* __restrict__ ET)
{
  __shared__ bf16_t tl[64][72];
  const int vb = blockIdx.x % (VOCAB / 64);
  const int eb = blockIdx.x / (VOCAB / 64);
  const int v0 = vb * 64, e0 = eb * 64;
  const int t = threadIdx.x;

  const int rr = t >> 4, c4 = (t & 15) * 4;
#pragma unroll
  for (int p = 0; p < 4; ++p) {
    const float* src = E + (size_t)(v0 + rr + p * 16) * DLAT + e0 + c4;
    f32x4 a = *(const f32x4*)src;
#pragma unroll
    for (int j = 0; j < 4; ++j) tl[c4 + j][rr + p * 16] = f2bf(a[j]);
  }
  __syncthreads();

  const int el = t >> 3, v8 = (t & 7) * 8;
#pragma unroll
  for (int p = 0; p < 2; ++p) {
    bf16x8 o = *(const bf16x8*)(&tl[el + p * 32][v8]);
    *(bf16x8*)(ET + (size_t)(e0 + el + p * 32) * VOCAB + v0 + v8) = o;
  }
}

// -------- LayerNorm over last dim (4096), f32 in -> bf16 out --------
__global__ void __launch_bounds__(256)
ln_k(const float* __restrict__ x, bf16_t* __restrict__ xn)
{
  __shared__ float sm[4];
  const int row = blockIdx.x, t = threadIdx.x;
  const float* xr = x + (size_t)row * DLAT;
  f32x4 v[4];
#pragma unroll
  for (int i = 0; i < 4; ++i) v[i] = *(const f32x4*)(xr + (t + i * 256) * 4);

  float s = 0.0f;
#pragma unroll
  for (int i = 0; i < 4; ++i)
#pragma unroll
    for (int j = 0; j < 4; ++j) s += v[i][j];
#pragma unroll
  for (int o = 32; o > 0; o >>= 1) s += __shfl_xor(s, o, 64);
  if ((t & 63) == 0) sm[t >> 6] = s;
  __syncthreads();
  const float mean = (sm[0] + sm[1] + sm[2] + sm[3]) * (1.0f / DLAT);
  __syncthreads();

  float qv = 0.0f;
#pragma unroll
  for (int i = 0; i < 4; ++i)
#pragma unroll
    for (int j = 0; j < 4; ++j) { float d = v[i][j] - mean; qv += d * d; }
#pragma unroll
  for (int o = 32; o > 0; o >>= 1) qv += __shfl_xor(qv, o, 64);
  if ((t & 63) == 0) sm[t >> 6] = qv;
  __syncthreads();
  const float varr = (sm[0] + sm[1] + sm[2] + sm[3]) * (1.0f / DLAT);
  const float rs = rsqrtf(varr + 1e-5f);

  bf16_t* outr = xn + (size_t)row * DLAT;
#pragma unroll
  for (int i = 0; i < 4; ++i) {
    bf16x4 o;
#pragma unroll
    for (int j = 0; j < 4; ++j) o[j] = f2bf((v[i][j] - mean) * rs);
    *(bf16x4*)(outr + (t + i * 256) * 4) = o;
  }
}

// -------- row softmax over V=32000, bf16 in-place, row staged in LDS --------
__global__ void __launch_bounds__(256)
softmax_k(bf16_t* __restrict__ L)
{
  __shared__ __align__(16) bf16_t rs_[VOCAB];
  __shared__ float sm[4];
  const int row = blockIdx.x, t = threadIdx.x;
  bf16_t* lrow = L + (size_t)row * VOCAB;
  const int NF = VOCAB / 8;

  float m = -3.0e38f;
  for (int f = t; f < NF; f += 256) {
    u16x8 u = *(const u16x8*)(&lrow[f * 8]);
    *(u16x8*)(&rs_[f * 8]) = u;
#pragma unroll
    for (int j = 0; j < 8; ++j) m = fmaxf(m, bf2f(u[j]));
  }
#pragma unroll
  for (int o = 32; o > 0; o >>= 1) m = fmaxf(m, __shfl_xor(m, o, 64));
  if ((t & 63) == 0) sm[t >> 6] = m;
  __syncthreads();
  m = fmaxf(fmaxf(sm[0], sm[1]), fmaxf(sm[2], sm[3]));
  __syncthreads();

  float s = 0.0f;
  for (int f = t; f < NF; f += 256) {
    u16x8 u = *(const u16x8*)(&rs_[f * 8]);
#pragma unroll
    for (int j = 0; j < 8; ++j) s += __expf(bf2f(u[j]) - m);
  }
#pragma unroll
  for (int o = 32; o > 0; o >>= 1) s += __shfl_xor(s, o, 64);
  if ((t & 63) == 0) sm[t >> 6] = s;
  __syncthreads();
  const float inv = 1.0f / (sm[0] + sm[1] + sm[2] + sm[3]);

  for (int f = t; f < NF; f += 256) {
    u16x8 u = *(const u16x8*)(&rs_[f * 8]);
    bf16x8 o;
#pragma unroll
    for (int j = 0; j < 8; ++j) o[j] = f2bf(__expf(bf2f(u[j]) - m) * inv);
    *(bf16x8*)(&lrow[f * 8]) = o;
  }
}

extern "C" void kernel_launch(void* const* d_in, const int* in_sizes, int n_in,
                              void* d_out, int out_size, void* d_ws, size_t ws_size,
                              hipStream_t stream)
{
  (void)in_sizes; (void)n_in; (void)out_size;
  const float* vision = (const float*)d_in[0];   // [2304][1024]
  const float* W1w    = (const float*)d_in[1];   // [4096][1024]
  const float* W1b    = (const float*)d_in[2];   // [4096]
  const float* W2w    = (const float*)d_in[3];   // [32000][4096]
  const float* Emb    = (const float*)d_in[4];   // [32000][4096]
  float* out = (float*)d_out;                    // [2304][4096]

  char* ws = (char*)d_ws;
  bf16_t* xn     = (bf16_t*)ws;                              //  18,874,368
  bf16_t* logits = (bf16_t*)(ws + 18874368);                 // 147,456,000
  float*  xbuf   = (float*)(ws + 166330368);                 //  37,748,736
  bf16_t* wslot  = (bf16_t*)(ws + 204079104);                // 262,144,000
  bf16_t* xnv    = (bf16_t*)(ws + 466223104);                //   4,718,592
  bf16_t* w1b    = (bf16_t*)(ws + 470941696);                //   8,388,608
  const size_t NEED = 479330304ull;

  const int Mt = M_TOK / GBM;  // 18

  if (ws_size >= NEED) {
    // 0) convert vision + W1 to bf16
    cvt_bf16_k<<<dim3(512), dim3(256), 0, stream>>>(vision, xnv, (long)M_TOK * DV / 8);
    cvt_bf16_k<<<dim3(512), dim3(256), 0, stream>>>(W1w, w1b, (long)DLAT * DV / 8);
    // 1) x = vision @ W1^T + b   (grid 576)
    gemm_bb<0><<<dim3(Mt * (DLAT / GBN)), dim3(256), 0, stream>>>(
        xnv, w1b, xbuf, W1b, DV, DLAT, Mt);
    // 2) xn = LayerNorm(x) -> bf16
    ln_k<<<dim3(M_TOK), dim3(256), 0, stream>>>(xbuf, xn);
    // 3a) W2 -> bf16
    cvt_bf16_k<<<dim3(2048), dim3(256), 0, stream>>>(W2w, wslot, (long)VOCAB * DLAT / 8);
    // 3b) logits = xn @ W2b^T -> bf16   (grid 4500)
    gemm_bb<1><<<dim3(Mt * (VOCAB / GBN)), dim3(256), 0, stream>>>(
        xn, wslot, logits, nullptr, DLAT, VOCAB, Mt);
    // 4) Emb -> EmbT bf16 [4096][32000] (reuses wslot)
    embT_k<<<dim3((VOCAB / 64) * (DLAT / 64)), dim3(256), 0, stream>>>(Emb, wslot);
    // 5) P = softmax(logits) in place
    softmax_k<<<dim3(M_TOK), dim3(256), 0, stream>>>(logits);
    // 6) out = P @ EmbT^T   (grid 576)
    gemm_bb<2><<<dim3(Mt * (DLAT / GBN)), dim3(256), 0, stream>>>(
        logits, wslot, out, nullptr, VOCAB, DLAT, Mt);
  } else {
    // --- fallback: R6 path ---
    gemm_k<1, 0, 0><<<dim3((M_TOK / BM) * (DLAT / BN)), dim3(256), 0, stream>>>(
        vision, W1w, xbuf, W1b, DV, DV, DV, DLAT, M_TOK / BM);
    ln_k<<<dim3(M_TOK), dim3(256), 0, stream>>>(xbuf, xn);
    gemm_k<0, 0, 1><<<dim3((M_TOK / BM) * (VOCAB / BN)), dim3(256), 0, stream>>>(
        xn, W2w, logits, nullptr, DLAT, DLAT, DLAT, VOCAB, M_TOK / BM);
    softmax_k<<<dim3(M_TOK), dim3(256), 0, stream>>>(logits);
    gemm_k<0, 1, 2><<<dim3((M_TOK / BM) * (DLAT / BN)), dim3(256), 0, stream>>>(
        logits, Emb, out, nullptr, VOCAB, VOCAB, DLAT, DLAT, M_TOK / BM);
  }
}